// Round 10
// baseline (250.116 us; speedup 1.0000x reference)
//
#include <hip/hip_runtime.h>
#include <hip/hip_bf16.h>

// EditOuterAttention — round 19.
// out = softmax((x Wq + bq)(y Wk + bk)^T / 8 + mask) (y Wv + bv) Wo + bo
// BS=2, LX=LY=2048, D=1024, H=16, DK=64.
//
// Round-19 delta:
//  - attn14 KEPT (passed; occupancy 2x'd but dur flat -> attn at LDS/latency two-sided
//    plateau ~49.6us; per-wave LDS traffic is structurally minimal).
//  - qkv8 -> qkv9: read-ahead interleave (m196/m201 lever). Every ds_read issued ONE
//    PHASE EARLY with counted lgkmcnt: q0 issues bf1 (lgkm 4), q1 issues af1 (lgkm 8),
//    q3 issues next tile's af0+bf0 (12; lgkm 12, free after q2's lgkm 0). Removes the
//    serial read-latency stall from every phase. Separate afA/afB/bfA/bfB register sets
//    (lifetimes verified: each overwritten only after last MFMA use). vmcnt schedule
//    BYTE-IDENTICAL to proven qkv8 (each VMW(8) lands exactly the stage the next read
//    needs; drain VMW(4)/(2)/(0) unchanged).
//  - prep / out_gemm unchanged.

typedef __bf16 bf16;
typedef __bf16 bf16x2 __attribute__((ext_vector_type(2)));
typedef __bf16 bf16x4 __attribute__((ext_vector_type(4)));
typedef __bf16 bf16x8 __attribute__((ext_vector_type(8)));
typedef float floatx4 __attribute__((ext_vector_type(4)));
typedef unsigned int uintx4 __attribute__((ext_vector_type(4)));

#define MFMA16(a, b, c) __builtin_amdgcn_mfma_f32_16x16x32_bf16(a, b, c, 0, 0, 0)

constexpr int BS = 2, LX = 2048, LY = 2048, D = 1024, H = 16, DK = 64;
constexpr int HD = H * DK;  // 1024
constexpr float LOG2E = 1.4426950408889634f;

__device__ __forceinline__ void cp16(const bf16* g, bf16* l) {
  __builtin_amdgcn_global_load_lds(
      (const __attribute__((address_space(1))) unsigned int*)g,
      (__attribute__((address_space(3))) unsigned int*)l, 16, 0, 0);
}

__device__ __forceinline__ unsigned pk2(float a, float b) {
  bf16x2 p;
  p[0] = (bf16)a;
  p[1] = (bf16)b;
  return __builtin_bit_cast(unsigned, p);
}

// ---------------- fused prep: weight transpose x4 | x,y bf16 convert | mask scan ----------------
__global__ __launch_bounds__(256) void prep(const float* __restrict__ W0, bf16* __restrict__ T0,
                                            const float* __restrict__ W1, bf16* __restrict__ T1,
                                            const float* __restrict__ W2, bf16* __restrict__ T2,
                                            const float* __restrict__ W3, bf16* __restrict__ T3,
                                            const float* __restrict__ x, bf16* __restrict__ xb,
                                            const float* __restrict__ y, bf16* __restrict__ yb,
                                            const float* __restrict__ mask, int* __restrict__ flags) {
  const int id = blockIdx.x;
  const int t = threadIdx.x;
  if (id < 1024) {
    __shared__ bf16 tile[64][72];
    const float* W;
    bf16* T;
    switch (id >> 8) {
      case 0: W = W0; T = T0; break;
      case 1: W = W1; T = T1; break;
      case 2: W = W2; T = T2; break;
      default: W = W3; T = T3; break;
    }
    const int kt = id & 15, nt = (id >> 4) & 15;
    const int r = t >> 2, c4 = (t & 3) * 16;
    const float* src = W + (size_t)(kt * 64 + r) * 1024 + nt * 64 + c4;
#pragma unroll
    for (int i = 0; i < 16; i++) tile[r][c4 + i] = (bf16)src[i];
    __syncthreads();
    bf16 vals[16];
#pragma unroll
    for (int i = 0; i < 16; i++) vals[i] = tile[c4 + i][r];
    bf16* dst = T + (size_t)(nt * 64 + r) * 1024 + kt * 64 + c4;
#pragma unroll
    for (int i = 0; i < 16; i++) dst[i] = vals[i];
  } else if (id < 5120) {
    const int id2 = id - 1024;
    const float* src = (id2 >= 2048) ? y : x;
    bf16* dst = (id2 >= 2048) ? yb : xb;
    const size_t i = ((size_t)(id2 & 2047) * 256 + t) * 8;
    float4 a = *(const float4*)(src + i);
    float4 c = *(const float4*)(src + i + 4);
    bf16 tmp[8] = {(bf16)a.x, (bf16)a.y, (bf16)a.z, (bf16)a.w,
                   (bf16)c.x, (bf16)c.y, (bf16)c.z, (bf16)c.w};
    *(bf16x8*)(dst + i) = *(const bf16x8*)tmp;
  } else {
    const int id3 = id - 5120;
    const int region = id3 >> 5, sub = id3 & 31;
    const float4* p = (const float4*)mask + (size_t)region * 65536 + sub * 2048;
    bool nz = false;
#pragma unroll
    for (int it = 0; it < 8; it++) {
      float4 v = p[it * 256 + t];
      nz |= (v.x != 0.f) | (v.y != 0.f) | (v.z != 0.f) | (v.w != 0.f);
    }
    if (nz) atomicOr(&flags[region], 1);
  }
}

// ---------------- fused QKV projection GEMM, round 19: 256^2, 4-phase, READ-AHEAD ----------------
// 8 waves 2Mx4N; per-wave C = 128x64. Phases per tile t (slot s=t%2):
//   q0: [stage B1(t+1)]  read bf1(s)   lgkm(4)  MFMA(0,0) afA,bfA
//   q1: [stage A1(t+1)]  read af1(s)   lgkm(8)  MFMA(0,1) afA,bfB
//   q2: [stage A0(t+2)]               lgkm(0)  MFMA(1,0) afB,bfA
//   q3: [stage B0(t+2)]  read af0,bf0(s') lgkm(12) MFMA(1,1) afB,bfB
// Every MFMA consumes reads issued >=1 phase earlier -> read latency hidden under MFMA.
// vmcnt(8) at q0/q1/q3 lands exactly the half-stage the next read needs (verified per
// phase); drain tiles 14/15 use VMW(4)/VMW(2)/VMW(0) as in qkv8.
__global__ __launch_bounds__(512, 2) void qkv9(const bf16* __restrict__ xb, const bf16* __restrict__ yb,
                                               const bf16* __restrict__ Wtq, const bf16* __restrict__ Wtk,
                                               const bf16* __restrict__ Wtv,
                                               const float* __restrict__ bq, const float* __restrict__ bk,
                                               const float* __restrict__ bv,
                                               bf16* __restrict__ Qb, bf16* __restrict__ Kb,
                                               bf16* __restrict__ Vt) {
  constexpr int K = 1024, N = 1024;
  __shared__ __align__(16) bf16 As[2][2][128 * 64];  // [tile-parity][half][row*64+k]
  __shared__ __align__(16) bf16 Bs[2][2][128 * 64];

  const int z = blockIdx.z;
  const bf16* A = (z == 0) ? xb : yb;
  const bf16* Bt = (z == 0) ? Wtq : (z == 1) ? Wtk : Wtv;
  const float* bias = (z == 0) ? bq : (z == 1) ? bk : bv;

  const int t = threadIdx.x;
  const int w = t >> 6, lane = t & 63, quad = lane >> 4, l15 = lane & 15;
  const int wm = w >> 2, wn = w & 3;
  const int mbase = blockIdx.y * 256, nbase = blockIdx.x * 256;
  const int srow = lane >> 3, schunk = (lane & 7) ^ srow;
  const int sx = quad ^ (l15 & 7);

  floatx4 acc[2][4][2][2] = {};
  bf16x8 afA[4][2], afB[4][2];  // A-frags: half0 / half1
  bf16x8 bfA[2][2], bfB[2][2];  // B-frags: half0 / half1

#define ST_A(ktt, half, slot)                                                                 \
  {                                                                                           \
    _Pragma("unroll") for (int j = 0; j < 2; j++) {                                           \
      const int r0 = w * 16 + j * 8;                                                          \
      cp16(A + (size_t)(mbase + (half) * 128 + r0 + srow) * K + (ktt) * 64 + schunk * 8,      \
           &As[slot][half][r0 * 64]);                                                         \
    }                                                                                         \
  }
#define ST_B(ktt, half, slot)                                                                 \
  {                                                                                           \
    _Pragma("unroll") for (int j = 0; j < 2; j++) {                                           \
      const int r0 = w * 16 + j * 8;                                                          \
      cp16(Bt + (size_t)(nbase + (half) * 128 + r0 + srow) * K + (ktt) * 64 + schunk * 8,     \
           &Bs[slot][half][r0 * 64]);                                                         \
    }                                                                                         \
  }
#define LDA(slot, half, DEST)                                                                 \
  {                                                                                           \
    _Pragma("unroll") for (int i = 0; i < 4; i++) {                                           \
      const bf16* p = &As[slot][half][(wm * 64 + i * 16 + l15) * 64];                         \
      DEST[i][0] = *(const bf16x8*)(p + sx * 8);                                              \
      DEST[i][1] = *(const bf16x8*)(p + (sx ^ 4) * 8);                                        \
    }                                                                                         \
  }
#define LDB(slot, half, DEST)                                                                 \
  {                                                                                           \
    _Pragma("unroll") for (int j = 0; j < 2; j++) {                                           \
      const bf16* p = &Bs[slot][half][(wn * 32 + j * 16 + l15) * 64];                         \
      DEST[j][0] = *(const bf16x8*)(p + sx * 8);                                              \
      DEST[j][1] = *(const bf16x8*)(p + (sx ^ 4) * 8);                                        \
    }                                                                                         \
  }
#define MFQ(mh, nh, AF, BF)                                                                   \
  {                                                                                           \
    _Pragma("unroll") for (int i = 0; i < 4; i++)                                             \
        _Pragma("unroll") for (int j = 0; j < 2; j++) {                                       \
      acc[mh][i][nh][j] = MFMA16(AF[i][0], BF[j][0], acc[mh][i][nh][j]);                      \
      acc[mh][i][nh][j] = MFMA16(AF[i][1], BF[j][1], acc[mh][i][nh][j]);                      \
    }                                                                                         \
  }
#define BARX()                       \
  {                                  \
    asm volatile("" ::: "memory");   \
    __builtin_amdgcn_s_barrier();    \
    asm volatile("" ::: "memory");   \
  }
#define VMW(n) asm volatile("s_waitcnt vmcnt(" #n ")" ::: "memory")
#define LGK(n) asm volatile("s_waitcnt lgkmcnt(" #n ")" ::: "memory")
#define NOPST {}
#define RDNORM(np) { LDA(np, 0, afA); LDB(np, 0, bfA); }
#define TILE_BODY(PAR, STG0, V0, STG1, V1, STG2, STG3, V3, RD3, LGQ3)  \
  {                                                         \
    STG0;                                                   \
    V0;                                                     \
    BARX();                                                 \
    LDB(PAR, 1, bfB);                                       \
    LGK(4);                                                 \
    __builtin_amdgcn_s_setprio(1);                          \
    MFQ(0, 0, afA, bfA);                                    \
    __builtin_amdgcn_s_setprio(0);                          \
    BARX();                                                 \
    STG1;                                                   \
    V1;                                                     \
    BARX();                                                 \
    LDA(PAR, 1, afB);                                       \
    LGK(8);                                                 \
    __builtin_amdgcn_s_setprio(1);                          \
    MFQ(0, 1, afA, bfB);                                    \
    __builtin_amdgcn_s_setprio(0);                          \
    BARX();                                                 \
    STG2;                                                   \
    BARX();                                                 \
    LGK(0);                                                 \
    __builtin_amdgcn_s_setprio(1);                          \
    MFQ(1, 0, afB, bfA);                                    \
    __builtin_amdgcn_s_setprio(0);                          \
    BARX();                                                 \
    STG3;                                                   \
    V3;                                                     \
    BARX();                                                 \
    RD3;                                                    \
    LGQ3;                                                   \
    __builtin_amdgcn_s_setprio(1);                          \
    MFQ(1, 1, afB, bfB);                                    \
    __builtin_amdgcn_s_setprio(0);                          \
    BARX();                                                 \
  }

  // prologue: issue A0(0),B0(0),B1(0),A1(0),A0(1),B0(1) = 6 half-stages (12 gloads);
  // VMW(8) -> oldest 4 (A0(0),B0(0)) landed; barrier publishes; then pre-read tile-0
  // af0/bf0 so tile-0 q0's MFMA consumes already-in-flight data.
  ST_A(0, 0, 0);
  ST_B(0, 0, 0);
  ST_B(0, 1, 0);
  ST_A(0, 1, 0);
  ST_A(1, 0, 1);
  ST_B(1, 0, 1);
  VMW(8);
  BARX();
  RDNORM(0);

#pragma unroll 1
  for (int kt = 0; kt < 14; kt += 2) {
    TILE_BODY(0, ST_B(kt + 1, 1, 1), VMW(8), ST_A(kt + 1, 1, 1), VMW(8),
              ST_A(kt + 2, 0, 0), ST_B(kt + 2, 0, 0), VMW(8), RDNORM(1), LGK(12));
    TILE_BODY(1, ST_B(kt + 2, 1, 0), VMW(8), ST_A(kt + 2, 1, 0), VMW(8),
              ST_A(kt + 3, 0, 1), ST_B(kt + 3, 0, 1), VMW(8), RDNORM(0), LGK(12));
  }
  // tile 14 (par 0): stages tile-15 B1/A1; q3 VMW(4) lands A0(15),B0(15) before RD3.
  TILE_BODY(0, ST_B(15, 1, 1), VMW(8), ST_A(15, 1, 1), VMW(8), NOPST, NOPST, VMW(4),
            RDNORM(1), LGK(12));
  // tile 15 (par 1): drain — q0 VMW(2) lands B1(15); q1 VMW(0) lands A1(15); no RD3.
  TILE_BODY(1, NOPST, VMW(2), NOPST, VMW(0), NOPST, NOPST, NOPST, NOPST, LGK(0));

#undef TILE_BODY
#undef RDNORM
#undef NOPST
#undef LGK
#undef VMW
#undef BARX
#undef MFQ
#undef LDB
#undef LDA
#undef ST_B
#undef ST_A

  if (z <= 1) {
    bf16* outp = (z == 0) ? Qb : Kb;
    const float sc = (z == 0) ? 0.125f * LOG2E : 1.0f;
#pragma unroll
    for (int nh = 0; nh < 2; nh++)
#pragma unroll
      for (int j = 0; j < 2; j++) {
        const int n = nbase + nh * 128 + wn * 32 + j * 16 + l15;
        const float bv2 = bias[n];
#pragma unroll
        for (int mh = 0; mh < 2; mh++)
#pragma unroll
          for (int i = 0; i < 4; i++)
#pragma unroll
            for (int r = 0; r < 4; r++) {
              const int m = mbase + mh * 128 + wm * 64 + i * 16 + quad * 4 + r;
              outp[(size_t)m * N + n] = (bf16)((acc[mh][i][nh][j][r] + bv2) * sc);
            }
      }
  } else {
    // V: store transposed into Vt (b,h,dk,y); 4 consecutive y per fragment -> bf16x4
    const int b = mbase >> 11;
    const int y0 = mbase & 2047;
#pragma unroll
    for (int nh = 0; nh < 2; nh++)
#pragma unroll
      for (int j = 0; j < 2; j++) {
        const int n = nbase + nh * 128 + wn * 32 + j * 16 + l15;
        const float bv2 = bias[n];
        const int hh = n >> 6, dk = n & 63;
        bf16* dst0 = Vt + ((size_t)(b * H + hh) * DK + dk) * LY + y0;
#pragma unroll
        for (int mh = 0; mh < 2; mh++)
#pragma unroll
          for (int i = 0; i < 4; i++) {
            const int yy = mh * 128 + wm * 64 + i * 16 + quad * 4;
            bf16 tmp[4];
#pragma unroll
            for (int r = 0; r < 4; r++) tmp[r] = (bf16)(acc[mh][i][nh][j][r] + bv2);
            *(bf16x4*)(dst0 + yy) = *(const bf16x4*)tmp;
          }
      }
  }
}

// ---------------- out GEMM: d_out = Hb @ Wo^T + bo (f32), 128M x 64N tiles (round-5 form) ----------------
__global__ __launch_bounds__(256) void out_gemm(const bf16* __restrict__ A, const bf16* __restrict__ Bt,
                                                const float* __restrict__ bias, float* __restrict__ outp) {
  constexpr int K = 1024, N = 1024;
  __shared__ __align__(16) bf16 As[128 * 64];
  __shared__ __align__(16) bf16 Bs[64 * 64];
  const int t = threadIdx.x;
  const int w = t >> 6, lane = t & 63, quad = lane >> 4, l15 = lane & 15;
  const int mbase = blockIdx.y * 128, nbase = blockIdx.x * 64;
  const int srow = lane >> 3, schunk = (lane & 7) ^ srow;
  const int sx = quad ^ (l15 & 7);

  floatx4 acc[2][4] = {};
  for (int k0 = 0; k0 < K; k0 += 64) {
    __syncthreads();
#pragma unroll
    for (int j = 0; j < 4; j++) {
      const int r0 = w * 32 + j * 8;
      cp16(A + (size_t)(mbase + r0 + srow) * K + k0 + schunk * 8, As + r0 * 64);
    }
#pragma unroll
    for (int j = 0; j < 2; j++) {
      const int r0 = w * 16 + j * 8;
      cp16(Bt + (size_t)(nbase + r0 + srow) * K + k0 + schunk * 8, Bs + r0 * 64);
    }
    __syncthreads();
    bf16x8 af[2][2], bfr[4][2];
#pragma unroll
    for (int i = 0; i < 2; i++) {
      const int ra = w * 32 + i * 16 + l15;
      af[i][0] = *(const bf16x8*)&As[ra * 64 + sx * 8];
      af[i][1] = *(const bf16x8*)&As[ra * 64 + (sx ^ 4) * 8];
    }
#pragma unroll
    for (int jn = 0; jn < 4; jn++) {
      const int rb = jn * 16 + l15;
      bfr[jn][0] = *(const bf16x8*)&Bs[rb * 64 + sx * 8];
      bfr[jn][1] = *(const bf16x8*)&Bs[rb * 64 + (sx ^ 4) * 8];
    }
#pragma unroll
    for (int i = 0; i < 2; i++)
#pragma unroll
      for (int jn = 0; jn < 4; jn++) {
        acc[i][jn] = MFMA16(af[i][0], bfr[jn][0], acc[i][jn]);
        acc[i][jn] = MFMA16(af[i][1], bfr[jn][1], acc[i][jn]);
      }
  }
#pragma unroll
  for (int jn = 0; jn < 4; jn++) {
    const int n = nbase + jn * 16 + l15;
    const float bv2 = bias[n];
#pragma unroll
    for (int i = 0; i < 2; i++)
#pragma unroll
      for (int r = 0; r < 4; r++) {
        const int m = mbase + w * 32 + i * 16 + quad * 4 + r;
        outp[(size_t)m * N + n] = acc[i][jn][r] + bv2;
      }
  }
}

// ---------------- flash attention, round 18 form (kept): QBLK=64, 4 blocks/CU ----------------
__global__ __launch_bounds__(256, 4) void attn14(const bf16* __restrict__ Q, const bf16* __restrict__ Kb,
                                                 const bf16* __restrict__ Vt, const float* __restrict__ mask,
                                                 const int* __restrict__ flags, bf16* __restrict__ Hout) {
  __shared__ __align__(16) bf16 Ks[2][64 * 64];
  __shared__ __align__(16) bf16 Vs[2][64 * 64];
  const int t = threadIdx.x;
  const int w = t >> 6, lane = t & 63, quad = lane >> 4, l15 = lane & 15;
  const int xt = blockIdx.x, h = blockIdx.y, b = blockIdx.z;
  const int qbase = xt * 64 + w * 16;
  const int srow = lane >> 3, schunk = (lane & 7) ^ srow;
  const int sx = quad ^ (l15 & 7);

  bf16x8 qf[2];
  {
    const bf16* qrow = Q + (size_t)(b * LX + qbase + l15) * HD + h * DK;
    qf[0] = *(const bf16x8*)(qrow + quad * 8);
    qf[1] = *(const bf16x8*)(qrow + 32 + quad * 8);
  }
  const int mflag = flags[b * 16 + (xt >> 1)];

  bf16 onearr[8];
#pragma unroll
  for (int i = 0; i < 8; i++) onearr[i] = (bf16)((l15 == 0) ? 1.0f : 0.0f);
  const bf16x8 onesf = *(const bf16x8*)onearr;

  floatx4 o[4] = {};
  floatx4 ol = {};

  const bf16* Kbase = Kb + (size_t)b * LY * HD + h * DK;
  const bf16* Vbase = Vt + (size_t)(b * H + h) * DK * LY;
  const float* mbase2 = mask + (size_t)(b * LX + qbase + l15) * LY;

#define STAGE(yt, bufi)                                                               \
  {                                                                                   \
    _Pragma("unroll") for (int j = 0; j < 2; j++) {                                   \
      const int r0 = w * 16 + j * 8;                                                  \
      cp16(Kbase + (size_t)((yt) + r0 + srow) * HD + schunk * 8, &Ks[bufi][r0 * 64]); \
      cp16(Vbase + (size_t)(r0 + srow) * LY + (yt) + schunk * 8, &Vs[bufi][r0 * 64]); \
    }                                                                                 \
  }

#define TILE(yt, BUF)                                                                       \
  {                                                                                         \
    const bf16* KsB = Ks[BUF];                                                              \
    const bf16* VsB = Vs[BUF];                                                              \
    bf16x8 kf[4][2];                                                                        \
    _Pragma("unroll") for (int nt = 0; nt < 4; nt++) {                                      \
      const int ry = nt * 16 + l15;                                                         \
      kf[nt][0] = *(const bf16x8*)&KsB[ry * 64 + sx * 8];                                   \
      kf[nt][1] = *(const bf16x8*)&KsB[ry * 64 + (sx ^ 4) * 8];                             \
    }                                                                                       \
    floatx4 s[4];                                                                           \
    __builtin_amdgcn_s_setprio(1);                                                          \
    _Pragma("unroll") for (int nt = 0; nt < 4; nt++) {                                      \
      floatx4 sz = {0.f, 0.f, 0.f, 0.f};                                                    \
      sz = MFMA16(kf[nt][0], qf[0], sz);                                                    \
      s[nt] = MFMA16(kf[nt][1], qf[1], sz);                                                 \
    }                                                                                       \
    __builtin_amdgcn_s_setprio(0);                                                          \
    if (mflag) {                                                                            \
      _Pragma("unroll") for (int nt = 0; nt < 4; nt++) {                                    \
        const float* mp = mbase2 + (yt) + nt * 16 + quad * 4;                               \
        float4 mv = *(const float4*)mp;                                                     \
        s[nt][0] = fminf(s[nt][0] + LOG2E * mv.x, 30.f);                                    \
        s[nt][1] = fminf(s[nt][1] + LOG2E * mv.y, 30.f);                                    \
        s[nt][2] = fminf(s[nt][2] + LOG2E * mv.z, 30.f);                                    \
        s[nt][3] = fminf(s[nt][3] + LOG2E * mv.w, 30.f);                                    \
      }                                                                                     \
    }                                                                                       \
    bf16x8 pf[2];                                                                           \
    {                                                                                       \
      uintx4 wd0, wd1;                                                                      \
      _Pragma("unroll") for (int F = 0; F < 2; F++)                                         \
          _Pragma("unroll") for (int hh = 0; hh < 2; hh++) {                                \
        unsigned wa = pk2(__builtin_amdgcn_exp2f(s[2 * F][2 * hh]),                         \
                          __builtin_amdgcn_exp2f(s[2 * F][2 * hh + 1]));                    \
        unsigned wb = pk2(__builtin_amdgcn_exp2f(s[2 * F + 1][2 * hh]),                     \
                          __builtin_amdgcn_exp2f(s[2 * F + 1][2 * hh + 1]));                \
        asm("v_permlane32_swap_b32 %0, %1" : "+v"(wa), "+v"(wb));                           \
        asm("v_permlane16_swap_b32 %0, %1" : "+v"(wa), "+v"(wb));                           \
        if (F == 0) {                                                                       \
          wd0[hh] = wa;                                                                     \
          wd0[hh + 2] = wb;                                                                 \
        } else {                                                                            \
          wd1[hh] = wa;                                                                     \
          wd1[hh + 2] = wb;                                                                 \
        }                                                                                   \
      }                                                                                     \
      pf[0] = __builtin_bit_cast(bf16x8, wd0);                                              \
      pf[1] = __builtin_bit_cast(bf16x8, wd1);                                              \
    }                                                                                       \
    __builtin_amdgcn_s_setprio(1);                                                          \
    _Pragma("unroll") for (int u = 0; u < 4; u++) {                                         \
      const int rd = u * 16 + l15;                                                          \
      bf16x8 v0 = *(const bf16x8*)&VsB[rd * 64 + sx * 8];                                   \
      bf16x8 v1 = *(const bf16x8*)&VsB[rd * 64 + (sx ^ 4) * 8];                             \
      o[u] = MFMA16(pf[0], v0, o[u]);                                                       \
      o[u] = MFMA16(pf[1], v1, o[u]);                                                       \
    }                                                                                       \
    ol = MFMA16(pf[0], onesf, ol);                                                          \
    ol = MFMA16(pf[1], onesf, ol);                                                          \
    __builtin_amdgcn_s_setprio(0);                                                          \
  }

  STAGE(0, 0);
  for (int yt = 0; yt < LY; yt += 128) {
    __syncthreads();
    STAGE(yt + 64, 1);
    TILE(yt, 0);
    __syncthreads();
    if (yt + 128 < LY) STAGE(yt + 128, 0);
    TILE(yt + 64, 1);
  }

#pragma unroll
  for (int r = 0; r < 4; r++) {
    const float lsum = __shfl(ol[r], lane & 48, 64);
    const float rl = 1.0f / lsum;
    const int m = b * LX + qbase + quad * 4 + r;
#pragma unroll
    for (int u = 0; u < 4; u++)
      Hout[(size_t)m * HD + h * DK + u * 16 + l15] = (bf16)(o[u][r] * rl);
  }
#undef STAGE
#undef TILE
}

// ---------------- launch ----------------
extern "C" void kernel_launch(void* const* d_in, const int* in_sizes, int n_in,
                              void* d_out, int out_size, void* d_ws, size_t ws_size,
                              hipStream_t stream) {
  const float* x = (const float*)d_in[0];
  const float* y = (const float*)d_in[1];
  const float* mask = (const float*)d_in[2];
  const float* Wq = (const float*)d_in[3];
  const float* bq = (const float*)d_in[4];
  const float* Wk = (const float*)d_in[5];
  const float* bk = (const float*)d_in[6];
  const float* Wv = (const float*)d_in[7];
  const float* bv = (const float*)d_in[8];
  const float* Wo = (const float*)d_in[9];
  const float* bo = (const float*)d_in[10];

  char* ws = (char*)d_ws;
  size_t off = 0;
  int* flags = (int*)(ws + off); off += 256;
  bf16* Qb = (bf16*)(ws + off); off += (size_t)BS * LX * HD * 2;
  bf16* Kb = (bf16*)(ws + off); off += (size_t)BS * LY * HD * 2;
  bf16* Vt = (bf16*)(ws + off); off += (size_t)BS * LY * HD * 2;  // (b,h,dk,y)
  bf16* Hb = (bf16*)(ws + off); off += (size_t)BS * LX * HD * 2;
  bf16* xbf = (bf16*)(ws + off); off += (size_t)BS * LX * D * 2;
  bf16* ybf = (bf16*)(ws + off); off += (size_t)BS * LY * D * 2;
  bf16* Wtq = (bf16*)(ws + off); off += (size_t)D * HD * 2;
  bf16* Wtk = (bf16*)(ws + off); off += (size_t)D * HD * 2;
  bf16* Wtv = (bf16*)(ws + off); off += (size_t)D * HD * 2;
  bf16* Wto = (bf16*)(ws + off); off += (size_t)HD * D * 2;

  dim3 blk(256);
  hipMemsetAsync(flags, 0, 32 * sizeof(int), stream);
  prep<<<dim3(6144), blk, 0, stream>>>(Wq, Wtq, Wk, Wtk, Wv, Wtv, Wo, Wto, x, xbf, y, ybf, mask, flags);
  qkv9<<<dim3(4, 16, 3), dim3(512), 0, stream>>>(xbf, ybf, Wtq, Wtk, Wtv, bq, bk, bv, Qb, Kb, Vt);
  attn14<<<dim3(32, 16, 2), blk, 0, stream>>>(Qb, Kb, Vt, mask, flags, Hb);
  out_gemm<<<dim3(16, 32), blk, 0, stream>>>(Hb, Wto, bo, (float*)d_out);
}

// Round 11
// 250.069 us; speedup vs baseline: 1.0002x; 1.0002x over previous
//
#include <hip/hip_runtime.h>
#include <hip/hip_bf16.h>

// EditOuterAttention — round 20.
// out = softmax((x Wq + bq)(y Wk + bk)^T / 8 + mask) (y Wv + bv) Wo + bo
// BS=2, LX=LY=2048, D=1024, H=16, DK=64.
//
// Round-20 delta:
//  - qkv9 spill fix: round-19's launch_bounds(512,2) capped VGPR at 128 while the
//    read-ahead needs ~180 -> scratch spill (WRITE_SIZE 25->65 MB, dur 50.7->74.8).
//    LDS (128 KiB) caps occupancy at 1 block/CU anyway, so the ",2" bought nothing.
//    Now __launch_bounds__(512): compiler free to ~190 VGPR, no spill, same occupancy.
//  - attn14 / prep / out_gemm unchanged.

typedef __bf16 bf16;
typedef __bf16 bf16x2 __attribute__((ext_vector_type(2)));
typedef __bf16 bf16x4 __attribute__((ext_vector_type(4)));
typedef __bf16 bf16x8 __attribute__((ext_vector_type(8)));
typedef float floatx4 __attribute__((ext_vector_type(4)));
typedef unsigned int uintx4 __attribute__((ext_vector_type(4)));

#define MFMA16(a, b, c) __builtin_amdgcn_mfma_f32_16x16x32_bf16(a, b, c, 0, 0, 0)

constexpr int BS = 2, LX = 2048, LY = 2048, D = 1024, H = 16, DK = 64;
constexpr int HD = H * DK;  // 1024
constexpr float LOG2E = 1.4426950408889634f;

__device__ __forceinline__ void cp16(const bf16* g, bf16* l) {
  __builtin_amdgcn_global_load_lds(
      (const __attribute__((address_space(1))) unsigned int*)g,
      (__attribute__((address_space(3))) unsigned int*)l, 16, 0, 0);
}

__device__ __forceinline__ unsigned pk2(float a, float b) {
  bf16x2 p;
  p[0] = (bf16)a;
  p[1] = (bf16)b;
  return __builtin_bit_cast(unsigned, p);
}

// ---------------- fused prep: weight transpose x4 | x,y bf16 convert | mask scan ----------------
__global__ __launch_bounds__(256) void prep(const float* __restrict__ W0, bf16* __restrict__ T0,
                                            const float* __restrict__ W1, bf16* __restrict__ T1,
                                            const float* __restrict__ W2, bf16* __restrict__ T2,
                                            const float* __restrict__ W3, bf16* __restrict__ T3,
                                            const float* __restrict__ x, bf16* __restrict__ xb,
                                            const float* __restrict__ y, bf16* __restrict__ yb,
                                            const float* __restrict__ mask, int* __restrict__ flags) {
  const int id = blockIdx.x;
  const int t = threadIdx.x;
  if (id < 1024) {
    __shared__ bf16 tile[64][72];
    const float* W;
    bf16* T;
    switch (id >> 8) {
      case 0: W = W0; T = T0; break;
      case 1: W = W1; T = T1; break;
      case 2: W = W2; T = T2; break;
      default: W = W3; T = T3; break;
    }
    const int kt = id & 15, nt = (id >> 4) & 15;
    const int r = t >> 2, c4 = (t & 3) * 16;
    const float* src = W + (size_t)(kt * 64 + r) * 1024 + nt * 64 + c4;
#pragma unroll
    for (int i = 0; i < 16; i++) tile[r][c4 + i] = (bf16)src[i];
    __syncthreads();
    bf16 vals[16];
#pragma unroll
    for (int i = 0; i < 16; i++) vals[i] = tile[c4 + i][r];
    bf16* dst = T + (size_t)(nt * 64 + r) * 1024 + kt * 64 + c4;
#pragma unroll
    for (int i = 0; i < 16; i++) dst[i] = vals[i];
  } else if (id < 5120) {
    const int id2 = id - 1024;
    const float* src = (id2 >= 2048) ? y : x;
    bf16* dst = (id2 >= 2048) ? yb : xb;
    const size_t i = ((size_t)(id2 & 2047) * 256 + t) * 8;
    float4 a = *(const float4*)(src + i);
    float4 c = *(const float4*)(src + i + 4);
    bf16 tmp[8] = {(bf16)a.x, (bf16)a.y, (bf16)a.z, (bf16)a.w,
                   (bf16)c.x, (bf16)c.y, (bf16)c.z, (bf16)c.w};
    *(bf16x8*)(dst + i) = *(const bf16x8*)tmp;
  } else {
    const int id3 = id - 5120;
    const int region = id3 >> 5, sub = id3 & 31;
    const float4* p = (const float4*)mask + (size_t)region * 65536 + sub * 2048;
    bool nz = false;
#pragma unroll
    for (int it = 0; it < 8; it++) {
      float4 v = p[it * 256 + t];
      nz |= (v.x != 0.f) | (v.y != 0.f) | (v.z != 0.f) | (v.w != 0.f);
    }
    if (nz) atomicOr(&flags[region], 1);
  }
}

// ---------------- fused QKV projection GEMM, round 20: 256^2, 4-phase, READ-AHEAD, no VGPR cap ----------------
// 8 waves 2Mx4N; per-wave C = 128x64. Phases per tile t (slot s=t%2):
//   q0: [stage B1(t+1)]  read bf1(s)   lgkm(4)  MFMA(0,0) afA,bfA
//   q1: [stage A1(t+1)]  read af1(s)   lgkm(8)  MFMA(0,1) afA,bfB
//   q2: [stage A0(t+2)]               lgkm(0)  MFMA(1,0) afB,bfA
//   q3: [stage B0(t+2)]  read af0,bf0(s') lgkm(12) MFMA(1,1) afB,bfB
// Every MFMA consumes reads issued >=1 phase earlier -> read latency hidden under MFMA.
// vmcnt(8) at q0/q1/q3 lands exactly the half-stage the next read needs; drain tiles
// 14/15 use VMW(4)/VMW(2)/VMW(0) as in qkv8.
__global__ __launch_bounds__(512) void qkv9(const bf16* __restrict__ xb, const bf16* __restrict__ yb,
                                            const bf16* __restrict__ Wtq, const bf16* __restrict__ Wtk,
                                            const bf16* __restrict__ Wtv,
                                            const float* __restrict__ bq, const float* __restrict__ bk,
                                            const float* __restrict__ bv,
                                            bf16* __restrict__ Qb, bf16* __restrict__ Kb,
                                            bf16* __restrict__ Vt) {
  constexpr int K = 1024, N = 1024;
  __shared__ __align__(16) bf16 As[2][2][128 * 64];  // [tile-parity][half][row*64+k]
  __shared__ __align__(16) bf16 Bs[2][2][128 * 64];

  const int z = blockIdx.z;
  const bf16* A = (z == 0) ? xb : yb;
  const bf16* Bt = (z == 0) ? Wtq : (z == 1) ? Wtk : Wtv;
  const float* bias = (z == 0) ? bq : (z == 1) ? bk : bv;

  const int t = threadIdx.x;
  const int w = t >> 6, lane = t & 63, quad = lane >> 4, l15 = lane & 15;
  const int wm = w >> 2, wn = w & 3;
  const int mbase = blockIdx.y * 256, nbase = blockIdx.x * 256;
  const int srow = lane >> 3, schunk = (lane & 7) ^ srow;
  const int sx = quad ^ (l15 & 7);

  floatx4 acc[2][4][2][2] = {};
  bf16x8 afA[4][2], afB[4][2];  // A-frags: half0 / half1
  bf16x8 bfA[2][2], bfB[2][2];  // B-frags: half0 / half1

#define ST_A(ktt, half, slot)                                                                 \
  {                                                                                           \
    _Pragma("unroll") for (int j = 0; j < 2; j++) {                                           \
      const int r0 = w * 16 + j * 8;                                                          \
      cp16(A + (size_t)(mbase + (half) * 128 + r0 + srow) * K + (ktt) * 64 + schunk * 8,      \
           &As[slot][half][r0 * 64]);                                                         \
    }                                                                                         \
  }
#define ST_B(ktt, half, slot)                                                                 \
  {                                                                                           \
    _Pragma("unroll") for (int j = 0; j < 2; j++) {                                           \
      const int r0 = w * 16 + j * 8;                                                          \
      cp16(Bt + (size_t)(nbase + (half) * 128 + r0 + srow) * K + (ktt) * 64 + schunk * 8,     \
           &Bs[slot][half][r0 * 64]);                                                         \
    }                                                                                         \
  }
#define LDA(slot, half, DEST)                                                                 \
  {                                                                                           \
    _Pragma("unroll") for (int i = 0; i < 4; i++) {                                           \
      const bf16* p = &As[slot][half][(wm * 64 + i * 16 + l15) * 64];                         \
      DEST[i][0] = *(const bf16x8*)(p + sx * 8);                                              \
      DEST[i][1] = *(const bf16x8*)(p + (sx ^ 4) * 8);                                        \
    }                                                                                         \
  }
#define LDB(slot, half, DEST)                                                                 \
  {                                                                                           \
    _Pragma("unroll") for (int j = 0; j < 2; j++) {                                           \
      const bf16* p = &Bs[slot][half][(wn * 32 + j * 16 + l15) * 64];                         \
      DEST[j][0] = *(const bf16x8*)(p + sx * 8);                                              \
      DEST[j][1] = *(const bf16x8*)(p + (sx ^ 4) * 8);                                        \
    }                                                                                         \
  }
#define MFQ(mh, nh, AF, BF)                                                                   \
  {                                                                                           \
    _Pragma("unroll") for (int i = 0; i < 4; i++)                                             \
        _Pragma("unroll") for (int j = 0; j < 2; j++) {                                       \
      acc[mh][i][nh][j] = MFMA16(AF[i][0], BF[j][0], acc[mh][i][nh][j]);                      \
      acc[mh][i][nh][j] = MFMA16(AF[i][1], BF[j][1], acc[mh][i][nh][j]);                      \
    }                                                                                         \
  }
#define BARX()                       \
  {                                  \
    asm volatile("" ::: "memory");   \
    __builtin_amdgcn_s_barrier();    \
    asm volatile("" ::: "memory");   \
  }
#define VMW(n) asm volatile("s_waitcnt vmcnt(" #n ")" ::: "memory")
#define LGK(n) asm volatile("s_waitcnt lgkmcnt(" #n ")" ::: "memory")
#define NOPST {}
#define RDNORM(np) { LDA(np, 0, afA); LDB(np, 0, bfA); }
#define TILE_BODY(PAR, STG0, V0, STG1, V1, STG2, STG3, V3, RD3, LGQ3)  \
  {                                                         \
    STG0;                                                   \
    V0;                                                     \
    BARX();                                                 \
    LDB(PAR, 1, bfB);                                       \
    LGK(4);                                                 \
    __builtin_amdgcn_s_setprio(1);                          \
    MFQ(0, 0, afA, bfA);                                    \
    __builtin_amdgcn_s_setprio(0);                          \
    BARX();                                                 \
    STG1;                                                   \
    V1;                                                     \
    BARX();                                                 \
    LDA(PAR, 1, afB);                                       \
    LGK(8);                                                 \
    __builtin_amdgcn_s_setprio(1);                          \
    MFQ(0, 1, afA, bfB);                                    \
    __builtin_amdgcn_s_setprio(0);                          \
    BARX();                                                 \
    STG2;                                                   \
    BARX();                                                 \
    LGK(0);                                                 \
    __builtin_amdgcn_s_setprio(1);                          \
    MFQ(1, 0, afB, bfA);                                    \
    __builtin_amdgcn_s_setprio(0);                          \
    BARX();                                                 \
    STG3;                                                   \
    V3;                                                     \
    BARX();                                                 \
    RD3;                                                    \
    LGQ3;                                                   \
    __builtin_amdgcn_s_setprio(1);                          \
    MFQ(1, 1, afB, bfB);                                    \
    __builtin_amdgcn_s_setprio(0);                          \
    BARX();                                                 \
  }

  // prologue: issue A0(0),B0(0),B1(0),A1(0),A0(1),B0(1) = 6 half-stages (12 gloads);
  // VMW(8) -> oldest 4 (A0(0),B0(0)) landed; barrier publishes; then pre-read tile-0
  // af0/bf0 so tile-0 q0's MFMA consumes already-in-flight data.
  ST_A(0, 0, 0);
  ST_B(0, 0, 0);
  ST_B(0, 1, 0);
  ST_A(0, 1, 0);
  ST_A(1, 0, 1);
  ST_B(1, 0, 1);
  VMW(8);
  BARX();
  RDNORM(0);

#pragma unroll 1
  for (int kt = 0; kt < 14; kt += 2) {
    TILE_BODY(0, ST_B(kt + 1, 1, 1), VMW(8), ST_A(kt + 1, 1, 1), VMW(8),
              ST_A(kt + 2, 0, 0), ST_B(kt + 2, 0, 0), VMW(8), RDNORM(1), LGK(12));
    TILE_BODY(1, ST_B(kt + 2, 1, 0), VMW(8), ST_A(kt + 2, 1, 0), VMW(8),
              ST_A(kt + 3, 0, 1), ST_B(kt + 3, 0, 1), VMW(8), RDNORM(0), LGK(12));
  }
  // tile 14 (par 0): stages tile-15 B1/A1; q3 VMW(4) lands A0(15),B0(15) before RD3.
  TILE_BODY(0, ST_B(15, 1, 1), VMW(8), ST_A(15, 1, 1), VMW(8), NOPST, NOPST, VMW(4),
            RDNORM(1), LGK(12));
  // tile 15 (par 1): drain — q0 VMW(2) lands B1(15); q1 VMW(0) lands A1(15); no RD3.
  TILE_BODY(1, NOPST, VMW(2), NOPST, VMW(0), NOPST, NOPST, NOPST, NOPST, LGK(0));

#undef TILE_BODY
#undef RDNORM
#undef NOPST
#undef LGK
#undef VMW
#undef BARX
#undef MFQ
#undef LDB
#undef LDA
#undef ST_B
#undef ST_A

  if (z <= 1) {
    bf16* outp = (z == 0) ? Qb : Kb;
    const float sc = (z == 0) ? 0.125f * LOG2E : 1.0f;
#pragma unroll
    for (int nh = 0; nh < 2; nh++)
#pragma unroll
      for (int j = 0; j < 2; j++) {
        const int n = nbase + nh * 128 + wn * 32 + j * 16 + l15;
        const float bv2 = bias[n];
#pragma unroll
        for (int mh = 0; mh < 2; mh++)
#pragma unroll
          for (int i = 0; i < 4; i++)
#pragma unroll
            for (int r = 0; r < 4; r++) {
              const int m = mbase + mh * 128 + wm * 64 + i * 16 + quad * 4 + r;
              outp[(size_t)m * N + n] = (bf16)((acc[mh][i][nh][j][r] + bv2) * sc);
            }
      }
  } else {
    // V: store transposed into Vt (b,h,dk,y); 4 consecutive y per fragment -> bf16x4
    const int b = mbase >> 11;
    const int y0 = mbase & 2047;
#pragma unroll
    for (int nh = 0; nh < 2; nh++)
#pragma unroll
      for (int j = 0; j < 2; j++) {
        const int n = nbase + nh * 128 + wn * 32 + j * 16 + l15;
        const float bv2 = bias[n];
        const int hh = n >> 6, dk = n & 63;
        bf16* dst0 = Vt + ((size_t)(b * H + hh) * DK + dk) * LY + y0;
#pragma unroll
        for (int mh = 0; mh < 2; mh++)
#pragma unroll
          for (int i = 0; i < 4; i++) {
            const int yy = mh * 128 + wm * 64 + i * 16 + quad * 4;
            bf16 tmp[4];
#pragma unroll
            for (int r = 0; r < 4; r++) tmp[r] = (bf16)(acc[mh][i][nh][j][r] + bv2);
            *(bf16x4*)(dst0 + yy) = *(const bf16x4*)tmp;
          }
      }
  }
}

// ---------------- out GEMM: d_out = Hb @ Wo^T + bo (f32), 128M x 64N tiles (round-5 form) ----------------
__global__ __launch_bounds__(256) void out_gemm(const bf16* __restrict__ A, const bf16* __restrict__ Bt,
                                                const float* __restrict__ bias, float* __restrict__ outp) {
  constexpr int K = 1024, N = 1024;
  __shared__ __align__(16) bf16 As[128 * 64];
  __shared__ __align__(16) bf16 Bs[64 * 64];
  const int t = threadIdx.x;
  const int w = t >> 6, lane = t & 63, quad = lane >> 4, l15 = lane & 15;
  const int mbase = blockIdx.y * 128, nbase = blockIdx.x * 64;
  const int srow = lane >> 3, schunk = (lane & 7) ^ srow;
  const int sx = quad ^ (l15 & 7);

  floatx4 acc[2][4] = {};
  for (int k0 = 0; k0 < K; k0 += 64) {
    __syncthreads();
#pragma unroll
    for (int j = 0; j < 4; j++) {
      const int r0 = w * 32 + j * 8;
      cp16(A + (size_t)(mbase + r0 + srow) * K + k0 + schunk * 8, As + r0 * 64);
    }
#pragma unroll
    for (int j = 0; j < 2; j++) {
      const int r0 = w * 16 + j * 8;
      cp16(Bt + (size_t)(nbase + r0 + srow) * K + k0 + schunk * 8, Bs + r0 * 64);
    }
    __syncthreads();
    bf16x8 af[2][2], bfr[4][2];
#pragma unroll
    for (int i = 0; i < 2; i++) {
      const int ra = w * 32 + i * 16 + l15;
      af[i][0] = *(const bf16x8*)&As[ra * 64 + sx * 8];
      af[i][1] = *(const bf16x8*)&As[ra * 64 + (sx ^ 4) * 8];
    }
#pragma unroll
    for (int jn = 0; jn < 4; jn++) {
      const int rb = jn * 16 + l15;
      bfr[jn][0] = *(const bf16x8*)&Bs[rb * 64 + sx * 8];
      bfr[jn][1] = *(const bf16x8*)&Bs[rb * 64 + (sx ^ 4) * 8];
    }
#pragma unroll
    for (int i = 0; i < 2; i++)
#pragma unroll
      for (int jn = 0; jn < 4; jn++) {
        acc[i][jn] = MFMA16(af[i][0], bfr[jn][0], acc[i][jn]);
        acc[i][jn] = MFMA16(af[i][1], bfr[jn][1], acc[i][jn]);
      }
  }
#pragma unroll
  for (int jn = 0; jn < 4; jn++) {
    const int n = nbase + jn * 16 + l15;
    const float bv2 = bias[n];
#pragma unroll
    for (int i = 0; i < 2; i++)
#pragma unroll
      for (int r = 0; r < 4; r++) {
        const int m = mbase + w * 32 + i * 16 + quad * 4 + r;
        outp[(size_t)m * N + n] = acc[i][jn][r] + bv2;
      }
  }
}

// ---------------- flash attention, round 18 form (kept): QBLK=64, 4 blocks/CU ----------------
__global__ __launch_bounds__(256, 4) void attn14(const bf16* __restrict__ Q, const bf16* __restrict__ Kb,
                                                 const bf16* __restrict__ Vt, const float* __restrict__ mask,
                                                 const int* __restrict__ flags, bf16* __restrict__ Hout) {
  __shared__ __align__(16) bf16 Ks[2][64 * 64];
  __shared__ __align__(16) bf16 Vs[2][64 * 64];
  const int t = threadIdx.x;
  const int w = t >> 6, lane = t & 63, quad = lane >> 4, l15 = lane & 15;
  const int xt = blockIdx.x, h = blockIdx.y, b = blockIdx.z;
  const int qbase = xt * 64 + w * 16;
  const int srow = lane >> 3, schunk = (lane & 7) ^ srow;
  const int sx = quad ^ (l15 & 7);

  bf16x8 qf[2];
  {
    const bf16* qrow = Q + (size_t)(b * LX + qbase + l15) * HD + h * DK;
    qf[0] = *(const bf16x8*)(qrow + quad * 8);
    qf[1] = *(const bf16x8*)(qrow + 32 + quad * 8);
  }
  const int mflag = flags[b * 16 + (xt >> 1)];

  bf16 onearr[8];
#pragma unroll
  for (int i = 0; i < 8; i++) onearr[i] = (bf16)((l15 == 0) ? 1.0f : 0.0f);
  const bf16x8 onesf = *(const bf16x8*)onearr;

  floatx4 o[4] = {};
  floatx4 ol = {};

  const bf16* Kbase = Kb + (size_t)b * LY * HD + h * DK;
  const bf16* Vbase = Vt + (size_t)(b * H + h) * DK * LY;
  const float* mbase2 = mask + (size_t)(b * LX + qbase + l15) * LY;

#define STAGE(yt, bufi)                                                               \
  {                                                                                   \
    _Pragma("unroll") for (int j = 0; j < 2; j++) {                                   \
      const int r0 = w * 16 + j * 8;                                                  \
      cp16(Kbase + (size_t)((yt) + r0 + srow) * HD + schunk * 8, &Ks[bufi][r0 * 64]); \
      cp16(Vbase + (size_t)(r0 + srow) * LY + (yt) + schunk * 8, &Vs[bufi][r0 * 64]); \
    }                                                                                 \
  }

#define TILE(yt, BUF)                                                                       \
  {                                                                                         \
    const bf16* KsB = Ks[BUF];                                                              \
    const bf16* VsB = Vs[BUF];                                                              \
    bf16x8 kf[4][2];                                                                        \
    _Pragma("unroll") for (int nt = 0; nt < 4; nt++) {                                      \
      const int ry = nt * 16 + l15;                                                         \
      kf[nt][0] = *(const bf16x8*)&KsB[ry * 64 + sx * 8];                                   \
      kf[nt][1] = *(const bf16x8*)&KsB[ry * 64 + (sx ^ 4) * 8];                             \
    }                                                                                       \
    floatx4 s[4];                                                                           \
    __builtin_amdgcn_s_setprio(1);                                                          \
    _Pragma("unroll") for (int nt = 0; nt < 4; nt++) {                                      \
      floatx4 sz = {0.f, 0.f, 0.f, 0.f};                                                    \
      sz = MFMA16(kf[nt][0], qf[0], sz);                                                    \
      s[nt] = MFMA16(kf[nt][1], qf[1], sz);                                                 \
    }                                                                                       \
    __builtin_amdgcn_s_setprio(0);                                                          \
    if (mflag) {                                                                            \
      _Pragma("unroll") for (int nt = 0; nt < 4; nt++) {                                    \
        const float* mp = mbase2 + (yt) + nt * 16 + quad * 4;                               \
        float4 mv = *(const float4*)mp;                                                     \
        s[nt][0] = fminf(s[nt][0] + LOG2E * mv.x, 30.f);                                    \
        s[nt][1] = fminf(s[nt][1] + LOG2E * mv.y, 30.f);                                    \
        s[nt][2] = fminf(s[nt][2] + LOG2E * mv.z, 30.f);                                    \
        s[nt][3] = fminf(s[nt][3] + LOG2E * mv.w, 30.f);                                    \
      }                                                                                     \
    }                                                                                       \
    bf16x8 pf[2];                                                                           \
    {                                                                                       \
      uintx4 wd0, wd1;                                                                      \
      _Pragma("unroll") for (int F = 0; F < 2; F++)                                         \
          _Pragma("unroll") for (int hh = 0; hh < 2; hh++) {                                \
        unsigned wa = pk2(__builtin_amdgcn_exp2f(s[2 * F][2 * hh]),                         \
                          __builtin_amdgcn_exp2f(s[2 * F][2 * hh + 1]));                    \
        unsigned wb = pk2(__builtin_amdgcn_exp2f(s[2 * F + 1][2 * hh]),                     \
                          __builtin_amdgcn_exp2f(s[2 * F + 1][2 * hh + 1]));                \
        asm("v_permlane32_swap_b32 %0, %1" : "+v"(wa), "+v"(wb));                           \
        asm("v_permlane16_swap_b32 %0, %1" : "+v"(wa), "+v"(wb));                           \
        if (F == 0) {                                                                       \
          wd0[hh] = wa;                                                                     \
          wd0[hh + 2] = wb;                                                                 \
        } else {                                                                            \
          wd1[hh] = wa;                                                                     \
          wd1[hh + 2] = wb;                                                                 \
        }                                                                                   \
      }                                                                                     \
      pf[0] = __builtin_bit_cast(bf16x8, wd0);                                              \
      pf[1] = __builtin_bit_cast(bf16x8, wd1);                                              \
    }                                                                                       \
    __builtin_amdgcn_s_setprio(1);                                                          \
    _Pragma("unroll") for (int u = 0; u < 4; u++) {                                         \
      const int rd = u * 16 + l15;                                                          \
      bf16x8 v0 = *(const bf16x8*)&VsB[rd * 64 + sx * 8];                                   \
      bf16x8 v1 = *(const bf16x8*)&VsB[rd * 64 + (sx ^ 4) * 8];                             \
      o[u] = MFMA16(pf[0], v0, o[u]);                                                       \
      o[u] = MFMA16(pf[1], v1, o[u]);                                                       \
    }                                                                                       \
    ol = MFMA16(pf[0], onesf, ol);                                                          \
    ol = MFMA16(pf[1], onesf, ol);                                                          \
    __builtin_amdgcn_s_setprio(0);                                                          \
  }

  STAGE(0, 0);
  for (int yt = 0; yt < LY; yt += 128) {
    __syncthreads();
    STAGE(yt + 64, 1);
    TILE(yt, 0);
    __syncthreads();
    if (yt + 128 < LY) STAGE(yt + 128, 0);
    TILE(yt + 64, 1);
  }

#pragma unroll
  for (int r = 0; r < 4; r++) {
    const float lsum = __shfl(ol[r], lane & 48, 64);
    const float rl = 1.0f / lsum;
    const int m = b * LX + qbase + quad * 4 + r;
#pragma unroll
    for (int u = 0; u < 4; u++)
      Hout[(size_t)m * HD + h * DK + u * 16 + l15] = (bf16)(o[u][r] * rl);
  }
#undef STAGE
#undef TILE
}

// ---------------- launch ----------------
extern "C" void kernel_launch(void* const* d_in, const int* in_sizes, int n_in,
                              void* d_out, int out_size, void* d_ws, size_t ws_size,
                              hipStream_t stream) {
  const float* x = (const float*)d_in[0];
  const float* y = (const float*)d_in[1];
  const float* mask = (const float*)d_in[2];
  const float* Wq = (const float*)d_in[3];
  const float* bq = (const float*)d_in[4];
  const float* Wk = (const float*)d_in[5];
  const float* bk = (const float*)d_in[6];
  const float* Wv = (const float*)d_in[7];
  const float* bv = (const float*)d_in[8];
  const float* Wo = (const float*)d_in[9];
  const float* bo = (const float*)d_in[10];

  char* ws = (char*)d_ws;
  size_t off = 0;
  int* flags = (int*)(ws + off); off += 256;
  bf16* Qb = (bf16*)(ws + off); off += (size_t)BS * LX * HD * 2;
  bf16* Kb = (bf16*)(ws + off); off += (size_t)BS * LY * HD * 2;
  bf16* Vt = (bf16*)(ws + off); off += (size_t)BS * LY * HD * 2;  // (b,h,dk,y)
  bf16* Hb = (bf16*)(ws + off); off += (size_t)BS * LX * HD * 2;
  bf16* xbf = (bf16*)(ws + off); off += (size_t)BS * LX * D * 2;
  bf16* ybf = (bf16*)(ws + off); off += (size_t)BS * LY * D * 2;
  bf16* Wtq = (bf16*)(ws + off); off += (size_t)D * HD * 2;
  bf16* Wtk = (bf16*)(ws + off); off += (size_t)D * HD * 2;
  bf16* Wtv = (bf16*)(ws + off); off += (size_t)D * HD * 2;
  bf16* Wto = (bf16*)(ws + off); off += (size_t)HD * D * 2;

  dim3 blk(256);
  hipMemsetAsync(flags, 0, 32 * sizeof(int), stream);
  prep<<<dim3(6144), blk, 0, stream>>>(Wq, Wtq, Wk, Wtk, Wv, Wtv, Wo, Wto, x, xbf, y, ybf, mask, flags);
  qkv9<<<dim3(4, 16, 3), dim3(512), 0, stream>>>(xbf, ybf, Wtq, Wtk, Wtv, bq, bk, bv, Qb, Kb, Vt);
  attn14<<<dim3(32, 16, 2), blk, 0, stream>>>(Qb, Kb, Vt, mask, flags, Hb);
  out_gemm<<<dim3(16, 32), blk, 0, stream>>>(Hb, Wto, bo, (float*)d_out);
}

// Round 12
// 236.650 us; speedup vs baseline: 1.0569x; 1.0567x over previous
//
#include <hip/hip_runtime.h>
#include <hip/hip_bf16.h>

// EditOuterAttention — round 21.
// out = softmax((x Wq + bq)(y Wk + bk)^T / 8 + mask) (y Wv + bv) Wo + bo
// BS=2, LX=LY=2048, D=1024, H=16, DK=64.
//
// Round-21 delta:
//  - qkv9 read-ahead branch DEAD (two configs, same 128-VGPR cap + 40MB spill; 66.9us).
//    qkv8 RESTORED byte-for-byte (proven 50.7us, fits 128 VGPR without spill).
//  - out_gemm -> out_gemm2: 128x64 tile upgraded to 128x128 (round-9-proven qkv_gemm
//    skeleton: same staging/swizzles/acc[4][4], 16 MFMA per barrier region instead of 8,
//    2/3 the staged bytes per FLOP). f32+bias epilogue. Grid (8,32)=256 -> 1 block/CU.
//  - prep / attn14 unchanged.

typedef __bf16 bf16;
typedef __bf16 bf16x2 __attribute__((ext_vector_type(2)));
typedef __bf16 bf16x4 __attribute__((ext_vector_type(4)));
typedef __bf16 bf16x8 __attribute__((ext_vector_type(8)));
typedef float floatx4 __attribute__((ext_vector_type(4)));
typedef unsigned int uintx4 __attribute__((ext_vector_type(4)));

#define MFMA16(a, b, c) __builtin_amdgcn_mfma_f32_16x16x32_bf16(a, b, c, 0, 0, 0)

constexpr int BS = 2, LX = 2048, LY = 2048, D = 1024, H = 16, DK = 64;
constexpr int HD = H * DK;  // 1024
constexpr float LOG2E = 1.4426950408889634f;

__device__ __forceinline__ void cp16(const bf16* g, bf16* l) {
  __builtin_amdgcn_global_load_lds(
      (const __attribute__((address_space(1))) unsigned int*)g,
      (__attribute__((address_space(3))) unsigned int*)l, 16, 0, 0);
}

__device__ __forceinline__ unsigned pk2(float a, float b) {
  bf16x2 p;
  p[0] = (bf16)a;
  p[1] = (bf16)b;
  return __builtin_bit_cast(unsigned, p);
}

// ---------------- fused prep: weight transpose x4 | x,y bf16 convert | mask scan ----------------
__global__ __launch_bounds__(256) void prep(const float* __restrict__ W0, bf16* __restrict__ T0,
                                            const float* __restrict__ W1, bf16* __restrict__ T1,
                                            const float* __restrict__ W2, bf16* __restrict__ T2,
                                            const float* __restrict__ W3, bf16* __restrict__ T3,
                                            const float* __restrict__ x, bf16* __restrict__ xb,
                                            const float* __restrict__ y, bf16* __restrict__ yb,
                                            const float* __restrict__ mask, int* __restrict__ flags) {
  const int id = blockIdx.x;
  const int t = threadIdx.x;
  if (id < 1024) {
    __shared__ bf16 tile[64][72];
    const float* W;
    bf16* T;
    switch (id >> 8) {
      case 0: W = W0; T = T0; break;
      case 1: W = W1; T = T1; break;
      case 2: W = W2; T = T2; break;
      default: W = W3; T = T3; break;
    }
    const int kt = id & 15, nt = (id >> 4) & 15;
    const int r = t >> 2, c4 = (t & 3) * 16;
    const float* src = W + (size_t)(kt * 64 + r) * 1024 + nt * 64 + c4;
#pragma unroll
    for (int i = 0; i < 16; i++) tile[r][c4 + i] = (bf16)src[i];
    __syncthreads();
    bf16 vals[16];
#pragma unroll
    for (int i = 0; i < 16; i++) vals[i] = tile[c4 + i][r];
    bf16* dst = T + (size_t)(nt * 64 + r) * 1024 + kt * 64 + c4;
#pragma unroll
    for (int i = 0; i < 16; i++) dst[i] = vals[i];
  } else if (id < 5120) {
    const int id2 = id - 1024;
    const float* src = (id2 >= 2048) ? y : x;
    bf16* dst = (id2 >= 2048) ? yb : xb;
    const size_t i = ((size_t)(id2 & 2047) * 256 + t) * 8;
    float4 a = *(const float4*)(src + i);
    float4 c = *(const float4*)(src + i + 4);
    bf16 tmp[8] = {(bf16)a.x, (bf16)a.y, (bf16)a.z, (bf16)a.w,
                   (bf16)c.x, (bf16)c.y, (bf16)c.z, (bf16)c.w};
    *(bf16x8*)(dst + i) = *(const bf16x8*)tmp;
  } else {
    const int id3 = id - 5120;
    const int region = id3 >> 5, sub = id3 & 31;
    const float4* p = (const float4*)mask + (size_t)region * 65536 + sub * 2048;
    bool nz = false;
#pragma unroll
    for (int it = 0; it < 8; it++) {
      float4 v = p[it * 256 + t];
      nz |= (v.x != 0.f) | (v.y != 0.f) | (v.z != 0.f) | (v.w != 0.f);
    }
    if (nz) atomicOr(&flags[region], 1);
  }
}

// ---------------- fused QKV projection GEMM, round 10 (RESTORED): 256^2, counted-vmcnt 4-phase ----------------
__global__ __launch_bounds__(512, 2) void qkv8(const bf16* __restrict__ xb, const bf16* __restrict__ yb,
                                               const bf16* __restrict__ Wtq, const bf16* __restrict__ Wtk,
                                               const bf16* __restrict__ Wtv,
                                               const float* __restrict__ bq, const float* __restrict__ bk,
                                               const float* __restrict__ bv,
                                               bf16* __restrict__ Qb, bf16* __restrict__ Kb,
                                               bf16* __restrict__ Vt) {
  constexpr int K = 1024, N = 1024;
  __shared__ __align__(16) bf16 As[2][2][128 * 64];  // [tile-parity][half][row*64+k]
  __shared__ __align__(16) bf16 Bs[2][2][128 * 64];

  const int z = blockIdx.z;
  const bf16* A = (z == 0) ? xb : yb;
  const bf16* Bt = (z == 0) ? Wtq : (z == 1) ? Wtk : Wtv;
  const float* bias = (z == 0) ? bq : (z == 1) ? bk : bv;

  const int t = threadIdx.x;
  const int w = t >> 6, lane = t & 63, quad = lane >> 4, l15 = lane & 15;
  const int wm = w >> 2, wn = w & 3;
  const int mbase = blockIdx.y * 256, nbase = blockIdx.x * 256;
  const int srow = lane >> 3, schunk = (lane & 7) ^ srow;
  const int sx = quad ^ (l15 & 7);

  floatx4 acc[2][4][2][2] = {};
  bf16x8 af[4][2];
  bf16x8 bfr[2][2][2];

#define ST_A(ktt, half, slot)                                                                 \
  {                                                                                           \
    _Pragma("unroll") for (int j = 0; j < 2; j++) {                                           \
      const int r0 = w * 16 + j * 8;                                                          \
      cp16(A + (size_t)(mbase + (half) * 128 + r0 + srow) * K + (ktt) * 64 + schunk * 8,      \
           &As[slot][half][r0 * 64]);                                                         \
    }                                                                                         \
  }
#define ST_B(ktt, half, slot)                                                                 \
  {                                                                                           \
    _Pragma("unroll") for (int j = 0; j < 2; j++) {                                           \
      const int r0 = w * 16 + j * 8;                                                          \
      cp16(Bt + (size_t)(nbase + (half) * 128 + r0 + srow) * K + (ktt) * 64 + schunk * 8,     \
           &Bs[slot][half][r0 * 64]);                                                         \
    }                                                                                         \
  }
#define LOAD_A(slot, mh)                                                                      \
  {                                                                                           \
    _Pragma("unroll") for (int i = 0; i < 4; i++) {                                           \
      const bf16* p = &As[slot][mh][(wm * 64 + i * 16 + l15) * 64];                           \
      af[i][0] = *(const bf16x8*)(p + sx * 8);                                                \
      af[i][1] = *(const bf16x8*)(p + (sx ^ 4) * 8);                                          \
    }                                                                                         \
  }
#define LOAD_B(slot, nh)                                                                      \
  {                                                                                           \
    _Pragma("unroll") for (int j = 0; j < 2; j++) {                                           \
      const bf16* p = &Bs[slot][nh][(wn * 32 + j * 16 + l15) * 64];                           \
      bfr[nh][j][0] = *(const bf16x8*)(p + sx * 8);                                           \
      bfr[nh][j][1] = *(const bf16x8*)(p + (sx ^ 4) * 8);                                     \
    }                                                                                         \
  }
#define MFMA_Q(mh, nh)                                                                        \
  {                                                                                           \
    _Pragma("unroll") for (int i = 0; i < 4; i++)                                             \
        _Pragma("unroll") for (int j = 0; j < 2; j++) {                                       \
      acc[mh][i][nh][j] = MFMA16(af[i][0], bfr[nh][j][0], acc[mh][i][nh][j]);                 \
      acc[mh][i][nh][j] = MFMA16(af[i][1], bfr[nh][j][1], acc[mh][i][nh][j]);                 \
    }                                                                                         \
  }
#define BARX()                       \
  {                                  \
    asm volatile("" ::: "memory");   \
    __builtin_amdgcn_s_barrier();    \
    asm volatile("" ::: "memory");   \
  }
#define VMW(n) asm volatile("s_waitcnt vmcnt(" #n ")" ::: "memory")
#define LG0() asm volatile("s_waitcnt lgkmcnt(0)" ::: "memory")
#define NOPST {}
#define TILE_BODY(PAR, STG0, V0, STG1, V1, STG2, STG3, V3)  \
  {                                                         \
    LOAD_A(PAR, 0);                                         \
    LOAD_B(PAR, 0);                                         \
    STG0;                                                   \
    V0;                                                     \
    BARX();                                                 \
    LG0();                                                  \
    __builtin_amdgcn_s_setprio(1);                          \
    MFMA_Q(0, 0);                                           \
    __builtin_amdgcn_s_setprio(0);                          \
    BARX();                                                 \
    LOAD_B(PAR, 1);                                         \
    STG1;                                                   \
    V1;                                                     \
    BARX();                                                 \
    LG0();                                                  \
    __builtin_amdgcn_s_setprio(1);                          \
    MFMA_Q(0, 1);                                           \
    __builtin_amdgcn_s_setprio(0);                          \
    BARX();                                                 \
    LOAD_A(PAR, 1);                                         \
    STG2;                                                   \
    BARX();                                                 \
    LG0();                                                  \
    __builtin_amdgcn_s_setprio(1);                          \
    MFMA_Q(1, 0);                                           \
    __builtin_amdgcn_s_setprio(0);                          \
    BARX();                                                 \
    STG3;                                                   \
    V3;                                                     \
    BARX();                                                 \
    LG0();                                                  \
    __builtin_amdgcn_s_setprio(1);                          \
    MFMA_Q(1, 1);                                           \
    __builtin_amdgcn_s_setprio(0);                          \
    BARX();                                                 \
  }

  // prologue: issue A0(0),B0(0),B1(0),A1(0),A0(1),B0(1) = 6 half-stages (12 loads);
  // vmcnt(8) -> oldest 4 loads (A0(0),B0(0)) landed, 4 half-stages stay in flight.
  ST_A(0, 0, 0);
  ST_B(0, 0, 0);
  ST_B(0, 1, 0);
  ST_A(0, 1, 0);
  ST_A(1, 0, 1);
  ST_B(1, 0, 1);
  VMW(8);
  BARX();

#pragma unroll 1
  for (int kt = 0; kt < 14; kt += 2) {
    TILE_BODY(0, ST_B(kt + 1, 1, 1), VMW(8), ST_A(kt + 1, 1, 1), VMW(8),
              ST_A(kt + 2, 0, 0), ST_B(kt + 2, 0, 0), VMW(8));
    TILE_BODY(1, ST_B(kt + 2, 1, 0), VMW(8), ST_A(kt + 2, 1, 0), VMW(8),
              ST_A(kt + 3, 0, 1), ST_B(kt + 3, 0, 1), VMW(8));
  }
  // kt = 14 (par 0): stages tile-15 B1/A1 only; q3 waits A0(15),B0(15) -> vmcnt(4)
  TILE_BODY(0, ST_B(15, 1, 1), VMW(8), ST_A(15, 1, 1), VMW(8), NOPST, NOPST, VMW(4));
  // kt = 15 (par 1): drain — q0 needs B1(15) -> vmcnt(2); q1 needs A1(15) -> vmcnt(0)
  TILE_BODY(1, NOPST, VMW(2), NOPST, VMW(0), NOPST, NOPST, NOPST);

#undef TILE_BODY
#undef NOPST
#undef LG0
#undef VMW
#undef BARX
#undef MFMA_Q
#undef LOAD_B
#undef LOAD_A
#undef ST_B
#undef ST_A

  if (z <= 1) {
    bf16* outp = (z == 0) ? Qb : Kb;
    const float sc = (z == 0) ? 0.125f * LOG2E : 1.0f;
#pragma unroll
    for (int nh = 0; nh < 2; nh++)
#pragma unroll
      for (int j = 0; j < 2; j++) {
        const int n = nbase + nh * 128 + wn * 32 + j * 16 + l15;
        const float bv2 = bias[n];
#pragma unroll
        for (int mh = 0; mh < 2; mh++)
#pragma unroll
          for (int i = 0; i < 4; i++)
#pragma unroll
            for (int r = 0; r < 4; r++) {
              const int m = mbase + mh * 128 + wm * 64 + i * 16 + quad * 4 + r;
              outp[(size_t)m * N + n] = (bf16)((acc[mh][i][nh][j][r] + bv2) * sc);
            }
      }
  } else {
    // V: store transposed into Vt (b,h,dk,y); 4 consecutive y per fragment -> bf16x4
    const int b = mbase >> 11;
    const int y0 = mbase & 2047;
#pragma unroll
    for (int nh = 0; nh < 2; nh++)
#pragma unroll
      for (int j = 0; j < 2; j++) {
        const int n = nbase + nh * 128 + wn * 32 + j * 16 + l15;
        const float bv2 = bias[n];
        const int hh = n >> 6, dk = n & 63;
        bf16* dst0 = Vt + ((size_t)(b * H + hh) * DK + dk) * LY + y0;
#pragma unroll
        for (int mh = 0; mh < 2; mh++)
#pragma unroll
          for (int i = 0; i < 4; i++) {
            const int yy = mh * 128 + wm * 64 + i * 16 + quad * 4;
            bf16 tmp[4];
#pragma unroll
            for (int r = 0; r < 4; r++) tmp[r] = (bf16)(acc[mh][i][nh][j][r] + bv2);
            *(bf16x4*)(dst0 + yy) = *(const bf16x4*)tmp;
          }
      }
  }
}

// ---------------- out GEMM round 21: 128x128 tile (round-9-proven skeleton), f32 epilogue ----------------
// d_out = Hb @ Wto^T + bo. Grid (8,32)=256 blocks -> 1/CU. 4 waves as 2x2 (64x64 each),
// acc[4][4]; 16 k-steps of BK=64; same staging swizzle as all proven GEMMs here.
__global__ __launch_bounds__(256) void out_gemm2(const bf16* __restrict__ A, const bf16* __restrict__ Bt,
                                                 const float* __restrict__ bias, float* __restrict__ outp) {
  constexpr int K = 1024, N = 1024;
  __shared__ __align__(16) bf16 As[128 * 64];
  __shared__ __align__(16) bf16 Bs[128 * 64];
  const int t = threadIdx.x;
  const int w = t >> 6, lane = t & 63, quad = lane >> 4, l15 = lane & 15;
  const int wr = (w & 1) * 64, wc = (w >> 1) * 64;
  const int mbase = blockIdx.y * 128, nbase = blockIdx.x * 128;
  const int srow = lane >> 3, schunk = (lane & 7) ^ srow;
  const int sx = quad ^ (l15 & 7);

  floatx4 acc[4][4] = {};

  for (int k0 = 0; k0 < K; k0 += 64) {
    __syncthreads();
#pragma unroll
    for (int j = 0; j < 4; j++) {
      const int r0 = w * 32 + j * 8;
      cp16(A + (size_t)(mbase + r0 + srow) * K + k0 + schunk * 8, As + r0 * 64);
      cp16(Bt + (size_t)(nbase + r0 + srow) * K + k0 + schunk * 8, Bs + r0 * 64);
    }
    __syncthreads();
    bf16x8 af[4][2], bfr[4][2];
#pragma unroll
    for (int i = 0; i < 4; i++) {
      const int ra = wr + i * 16 + l15;
      af[i][0] = *(const bf16x8*)&As[ra * 64 + sx * 8];
      af[i][1] = *(const bf16x8*)&As[ra * 64 + (sx ^ 4) * 8];
      const int rb = wc + i * 16 + l15;
      bfr[i][0] = *(const bf16x8*)&Bs[rb * 64 + sx * 8];
      bfr[i][1] = *(const bf16x8*)&Bs[rb * 64 + (sx ^ 4) * 8];
    }
#pragma unroll
    for (int i = 0; i < 4; i++)
#pragma unroll
      for (int jn = 0; jn < 4; jn++) {
        acc[i][jn] = MFMA16(af[i][0], bfr[jn][0], acc[i][jn]);
        acc[i][jn] = MFMA16(af[i][1], bfr[jn][1], acc[i][jn]);
      }
  }

#pragma unroll
  for (int jn = 0; jn < 4; jn++) {
    const int n = nbase + wc + jn * 16 + l15;
    const float bv2 = bias[n];
#pragma unroll
    for (int i = 0; i < 4; i++)
#pragma unroll
      for (int r = 0; r < 4; r++) {
        const int m = mbase + wr + i * 16 + quad * 4 + r;
        outp[(size_t)m * N + n] = acc[i][jn][r] + bv2;
      }
  }
}

// ---------------- flash attention, round 18 form (kept): QBLK=64, 4 blocks/CU ----------------
__global__ __launch_bounds__(256, 4) void attn14(const bf16* __restrict__ Q, const bf16* __restrict__ Kb,
                                                 const bf16* __restrict__ Vt, const float* __restrict__ mask,
                                                 const int* __restrict__ flags, bf16* __restrict__ Hout) {
  __shared__ __align__(16) bf16 Ks[2][64 * 64];
  __shared__ __align__(16) bf16 Vs[2][64 * 64];
  const int t = threadIdx.x;
  const int w = t >> 6, lane = t & 63, quad = lane >> 4, l15 = lane & 15;
  const int xt = blockIdx.x, h = blockIdx.y, b = blockIdx.z;
  const int qbase = xt * 64 + w * 16;
  const int srow = lane >> 3, schunk = (lane & 7) ^ srow;
  const int sx = quad ^ (l15 & 7);

  bf16x8 qf[2];
  {
    const bf16* qrow = Q + (size_t)(b * LX + qbase + l15) * HD + h * DK;
    qf[0] = *(const bf16x8*)(qrow + quad * 8);
    qf[1] = *(const bf16x8*)(qrow + 32 + quad * 8);
  }
  const int mflag = flags[b * 16 + (xt >> 1)];

  bf16 onearr[8];
#pragma unroll
  for (int i = 0; i < 8; i++) onearr[i] = (bf16)((l15 == 0) ? 1.0f : 0.0f);
  const bf16x8 onesf = *(const bf16x8*)onearr;

  floatx4 o[4] = {};
  floatx4 ol = {};

  const bf16* Kbase = Kb + (size_t)b * LY * HD + h * DK;
  const bf16* Vbase = Vt + (size_t)(b * H + h) * DK * LY;
  const float* mbase2 = mask + (size_t)(b * LX + qbase + l15) * LY;

#define STAGE(yt, bufi)                                                               \
  {                                                                                   \
    _Pragma("unroll") for (int j = 0; j < 2; j++) {                                   \
      const int r0 = w * 16 + j * 8;                                                  \
      cp16(Kbase + (size_t)((yt) + r0 + srow) * HD + schunk * 8, &Ks[bufi][r0 * 64]); \
      cp16(Vbase + (size_t)(r0 + srow) * LY + (yt) + schunk * 8, &Vs[bufi][r0 * 64]); \
    }                                                                                 \
  }

#define TILE(yt, BUF)                                                                       \
  {                                                                                         \
    const bf16* KsB = Ks[BUF];                                                              \
    const bf16* VsB = Vs[BUF];                                                              \
    bf16x8 kf[4][2];                                                                        \
    _Pragma("unroll") for (int nt = 0; nt < 4; nt++) {                                      \
      const int ry = nt * 16 + l15;                                                         \
      kf[nt][0] = *(const bf16x8*)&KsB[ry * 64 + sx * 8];                                   \
      kf[nt][1] = *(const bf16x8*)&KsB[ry * 64 + (sx ^ 4) * 8];                             \
    }                                                                                       \
    floatx4 s[4];                                                                           \
    __builtin_amdgcn_s_setprio(1);                                                          \
    _Pragma("unroll") for (int nt = 0; nt < 4; nt++) {                                      \
      floatx4 sz = {0.f, 0.f, 0.f, 0.f};                                                    \
      sz = MFMA16(kf[nt][0], qf[0], sz);                                                    \
      s[nt] = MFMA16(kf[nt][1], qf[1], sz);                                                 \
    }                                                                                       \
    __builtin_amdgcn_s_setprio(0);                                                          \
    if (mflag) {                                                                            \
      _Pragma("unroll") for (int nt = 0; nt < 4; nt++) {                                    \
        const float* mp = mbase2 + (yt) + nt * 16 + quad * 4;                               \
        float4 mv = *(const float4*)mp;                                                     \
        s[nt][0] = fminf(s[nt][0] + LOG2E * mv.x, 30.f);                                    \
        s[nt][1] = fminf(s[nt][1] + LOG2E * mv.y, 30.f);                                    \
        s[nt][2] = fminf(s[nt][2] + LOG2E * mv.z, 30.f);                                    \
        s[nt][3] = fminf(s[nt][3] + LOG2E * mv.w, 30.f);                                    \
      }                                                                                     \
    }                                                                                       \
    bf16x8 pf[2];                                                                           \
    {                                                                                       \
      uintx4 wd0, wd1;                                                                      \
      _Pragma("unroll") for (int F = 0; F < 2; F++)                                         \
          _Pragma("unroll") for (int hh = 0; hh < 2; hh++) {                                \
        unsigned wa = pk2(__builtin_amdgcn_exp2f(s[2 * F][2 * hh]),                         \
                          __builtin_amdgcn_exp2f(s[2 * F][2 * hh + 1]));                    \
        unsigned wb = pk2(__builtin_amdgcn_exp2f(s[2 * F + 1][2 * hh]),                     \
                          __builtin_amdgcn_exp2f(s[2 * F + 1][2 * hh + 1]));                \
        asm("v_permlane32_swap_b32 %0, %1" : "+v"(wa), "+v"(wb));                           \
        asm("v_permlane16_swap_b32 %0, %1" : "+v"(wa), "+v"(wb));                           \
        if (F == 0) {                                                                       \
          wd0[hh] = wa;                                                                     \
          wd0[hh + 2] = wb;                                                                 \
        } else {                                                                            \
          wd1[hh] = wa;                                                                     \
          wd1[hh + 2] = wb;                                                                 \
        }                                                                                   \
      }                                                                                     \
      pf[0] = __builtin_bit_cast(bf16x8, wd0);                                              \
      pf[1] = __builtin_bit_cast(bf16x8, wd1);                                              \
    }                                                                                       \
    __builtin_amdgcn_s_setprio(1);                                                          \
    _Pragma("unroll") for (int u = 0; u < 4; u++) {                                         \
      const int rd = u * 16 + l15;                                                          \
      bf16x8 v0 = *(const bf16x8*)&VsB[rd * 64 + sx * 8];                                   \
      bf16x8 v1 = *(const bf16x8*)&VsB[rd * 64 + (sx ^ 4) * 8];                             \
      o[u] = MFMA16(pf[0], v0, o[u]);                                                       \
      o[u] = MFMA16(pf[1], v1, o[u]);                                                       \
    }                                                                                       \
    ol = MFMA16(pf[0], onesf, ol);                                                          \
    ol = MFMA16(pf[1], onesf, ol);                                                          \
    __builtin_amdgcn_s_setprio(0);                                                          \
  }

  STAGE(0, 0);
  for (int yt = 0; yt < LY; yt += 128) {
    __syncthreads();
    STAGE(yt + 64, 1);
    TILE(yt, 0);
    __syncthreads();
    if (yt + 128 < LY) STAGE(yt + 128, 0);
    TILE(yt + 64, 1);
  }

#pragma unroll
  for (int r = 0; r < 4; r++) {
    const float lsum = __shfl(ol[r], lane & 48, 64);
    const float rl = 1.0f / lsum;
    const int m = b * LX + qbase + quad * 4 + r;
#pragma unroll
    for (int u = 0; u < 4; u++)
      Hout[(size_t)m * HD + h * DK + u * 16 + l15] = (bf16)(o[u][r] * rl);
  }
#undef STAGE
#undef TILE
}

// ---------------- launch ----------------
extern "C" void kernel_launch(void* const* d_in, const int* in_sizes, int n_in,
                              void* d_out, int out_size, void* d_ws, size_t ws_size,
                              hipStream_t stream) {
  const float* x = (const float*)d_in[0];
  const float* y = (const float*)d_in[1];
  const float* mask = (const float*)d_in[2];
  const float* Wq = (const float*)d_in[3];
  const float* bq = (const float*)d_in[4];
  const float* Wk = (const float*)d_in[5];
  const float* bk = (const float*)d_in[6];
  const float* Wv = (const float*)d_in[7];
  const float* bv = (const float*)d_in[8];
  const float* Wo = (const float*)d_in[9];
  const float* bo = (const float*)d_in[10];

  char* ws = (char*)d_ws;
  size_t off = 0;
  int* flags = (int*)(ws + off); off += 256;
  bf16* Qb = (bf16*)(ws + off); off += (size_t)BS * LX * HD * 2;
  bf16* Kb = (bf16*)(ws + off); off += (size_t)BS * LY * HD * 2;
  bf16* Vt = (bf16*)(ws + off); off += (size_t)BS * LY * HD * 2;  // (b,h,dk,y)
  bf16* Hb = (bf16*)(ws + off); off += (size_t)BS * LX * HD * 2;
  bf16* xbf = (bf16*)(ws + off); off += (size_t)BS * LX * D * 2;
  bf16* ybf = (bf16*)(ws + off); off += (size_t)BS * LY * D * 2;
  bf16* Wtq = (bf16*)(ws + off); off += (size_t)D * HD * 2;
  bf16* Wtk = (bf16*)(ws + off); off += (size_t)D * HD * 2;
  bf16* Wtv = (bf16*)(ws + off); off += (size_t)D * HD * 2;
  bf16* Wto = (bf16*)(ws + off); off += (size_t)HD * D * 2;

  dim3 blk(256);
  hipMemsetAsync(flags, 0, 32 * sizeof(int), stream);
  prep<<<dim3(6144), blk, 0, stream>>>(Wq, Wtq, Wk, Wtk, Wv, Wtv, Wo, Wto, x, xbf, y, ybf, mask, flags);
  qkv8<<<dim3(4, 16, 3), dim3(512), 0, stream>>>(xbf, ybf, Wtq, Wtk, Wtv, bq, bk, bv, Qb, Kb, Vt);
  attn14<<<dim3(32, 16, 2), blk, 0, stream>>>(Qb, Kb, Vt, mask, flags, Hb);
  out_gemm2<<<dim3(8, 32), blk, 0, stream>>>(Hb, Wto, bo, (float*)d_out);
}

// Round 13
// 222.939 us; speedup vs baseline: 1.1219x; 1.0615x over previous
//
#include <hip/hip_runtime.h>
#include <hip/hip_bf16.h>

// EditOuterAttention — round 22 (FINAL: revert to session-best measured config, round 15).
// out = softmax((x Wq + bq)(y Wk + bk)^T / 8 + mask) (y Wv + bv) Wo + bo
// BS=2, LX=LY=2048, D=1024, H=16, DK=64.
//
// Config: prep | qkv8 (256^2 4-phase counted-vmcnt) | attn12 (deferred softmax,
// QBLK=128, 2-buffer) | out_gemm (128x64, 2 blocks/CU). Measured 224.06 us (round 15).
//  - out_gemm2 (128x128) REVERTED: grid 256 = 1 block/CU lost the 2-block implicit
//    overlap -> +7 us total. 128x64 @ 512 blocks is structurally right for this shape.
//  - attn plateau ~49.6-50.8 us proven two-sided (occupancy-doubling falsification);
//    qkv read-ahead dead (128-VGPR wall, 2 attempts).

typedef __bf16 bf16;
typedef __bf16 bf16x2 __attribute__((ext_vector_type(2)));
typedef __bf16 bf16x4 __attribute__((ext_vector_type(4)));
typedef __bf16 bf16x8 __attribute__((ext_vector_type(8)));
typedef float floatx4 __attribute__((ext_vector_type(4)));
typedef unsigned int uintx4 __attribute__((ext_vector_type(4)));

#define MFMA16(a, b, c) __builtin_amdgcn_mfma_f32_16x16x32_bf16(a, b, c, 0, 0, 0)

constexpr int BS = 2, LX = 2048, LY = 2048, D = 1024, H = 16, DK = 64;
constexpr int HD = H * DK;  // 1024
constexpr float LOG2E = 1.4426950408889634f;

__device__ __forceinline__ void cp16(const bf16* g, bf16* l) {
  __builtin_amdgcn_global_load_lds(
      (const __attribute__((address_space(1))) unsigned int*)g,
      (__attribute__((address_space(3))) unsigned int*)l, 16, 0, 0);
}

__device__ __forceinline__ unsigned pk2(float a, float b) {
  bf16x2 p;
  p[0] = (bf16)a;
  p[1] = (bf16)b;
  return __builtin_bit_cast(unsigned, p);
}

// ---------------- fused prep: weight transpose x4 | x,y bf16 convert | mask scan ----------------
__global__ __launch_bounds__(256) void prep(const float* __restrict__ W0, bf16* __restrict__ T0,
                                            const float* __restrict__ W1, bf16* __restrict__ T1,
                                            const float* __restrict__ W2, bf16* __restrict__ T2,
                                            const float* __restrict__ W3, bf16* __restrict__ T3,
                                            const float* __restrict__ x, bf16* __restrict__ xb,
                                            const float* __restrict__ y, bf16* __restrict__ yb,
                                            const float* __restrict__ mask, int* __restrict__ flags) {
  const int id = blockIdx.x;
  const int t = threadIdx.x;
  if (id < 1024) {
    __shared__ bf16 tile[64][72];
    const float* W;
    bf16* T;
    switch (id >> 8) {
      case 0: W = W0; T = T0; break;
      case 1: W = W1; T = T1; break;
      case 2: W = W2; T = T2; break;
      default: W = W3; T = T3; break;
    }
    const int kt = id & 15, nt = (id >> 4) & 15;
    const int r = t >> 2, c4 = (t & 3) * 16;
    const float* src = W + (size_t)(kt * 64 + r) * 1024 + nt * 64 + c4;
#pragma unroll
    for (int i = 0; i < 16; i++) tile[r][c4 + i] = (bf16)src[i];
    __syncthreads();
    bf16 vals[16];
#pragma unroll
    for (int i = 0; i < 16; i++) vals[i] = tile[c4 + i][r];
    bf16* dst = T + (size_t)(nt * 64 + r) * 1024 + kt * 64 + c4;
#pragma unroll
    for (int i = 0; i < 16; i++) dst[i] = vals[i];
  } else if (id < 5120) {
    const int id2 = id - 1024;
    const float* src = (id2 >= 2048) ? y : x;
    bf16* dst = (id2 >= 2048) ? yb : xb;
    const size_t i = ((size_t)(id2 & 2047) * 256 + t) * 8;
    float4 a = *(const float4*)(src + i);
    float4 c = *(const float4*)(src + i + 4);
    bf16 tmp[8] = {(bf16)a.x, (bf16)a.y, (bf16)a.z, (bf16)a.w,
                   (bf16)c.x, (bf16)c.y, (bf16)c.z, (bf16)c.w};
    *(bf16x8*)(dst + i) = *(const bf16x8*)tmp;
  } else {
    const int id3 = id - 5120;
    const int region = id3 >> 5, sub = id3 & 31;
    const float4* p = (const float4*)mask + (size_t)region * 65536 + sub * 2048;
    bool nz = false;
#pragma unroll
    for (int it = 0; it < 8; it++) {
      float4 v = p[it * 256 + t];
      nz |= (v.x != 0.f) | (v.y != 0.f) | (v.z != 0.f) | (v.w != 0.f);
    }
    if (nz) atomicOr(&flags[region], 1);
  }
}

// ---------------- fused QKV projection GEMM: 256^2 tile, BK=64, counted-vmcnt 4-phase ----------------
__global__ __launch_bounds__(512, 2) void qkv8(const bf16* __restrict__ xb, const bf16* __restrict__ yb,
                                               const bf16* __restrict__ Wtq, const bf16* __restrict__ Wtk,
                                               const bf16* __restrict__ Wtv,
                                               const float* __restrict__ bq, const float* __restrict__ bk,
                                               const float* __restrict__ bv,
                                               bf16* __restrict__ Qb, bf16* __restrict__ Kb,
                                               bf16* __restrict__ Vt) {
  constexpr int K = 1024, N = 1024;
  __shared__ __align__(16) bf16 As[2][2][128 * 64];  // [tile-parity][half][row*64+k]
  __shared__ __align__(16) bf16 Bs[2][2][128 * 64];

  const int z = blockIdx.z;
  const bf16* A = (z == 0) ? xb : yb;
  const bf16* Bt = (z == 0) ? Wtq : (z == 1) ? Wtk : Wtv;
  const float* bias = (z == 0) ? bq : (z == 1) ? bk : bv;

  const int t = threadIdx.x;
  const int w = t >> 6, lane = t & 63, quad = lane >> 4, l15 = lane & 15;
  const int wm = w >> 2, wn = w & 3;
  const int mbase = blockIdx.y * 256, nbase = blockIdx.x * 256;
  const int srow = lane >> 3, schunk = (lane & 7) ^ srow;
  const int sx = quad ^ (l15 & 7);

  floatx4 acc[2][4][2][2] = {};
  bf16x8 af[4][2];
  bf16x8 bfr[2][2][2];

#define ST_A(ktt, half, slot)                                                                 \
  {                                                                                           \
    _Pragma("unroll") for (int j = 0; j < 2; j++) {                                           \
      const int r0 = w * 16 + j * 8;                                                          \
      cp16(A + (size_t)(mbase + (half) * 128 + r0 + srow) * K + (ktt) * 64 + schunk * 8,      \
           &As[slot][half][r0 * 64]);                                                         \
    }                                                                                         \
  }
#define ST_B(ktt, half, slot)                                                                 \
  {                                                                                           \
    _Pragma("unroll") for (int j = 0; j < 2; j++) {                                           \
      const int r0 = w * 16 + j * 8;                                                          \
      cp16(Bt + (size_t)(nbase + (half) * 128 + r0 + srow) * K + (ktt) * 64 + schunk * 8,     \
           &Bs[slot][half][r0 * 64]);                                                         \
    }                                                                                         \
  }
#define LOAD_A(slot, mh)                                                                      \
  {                                                                                           \
    _Pragma("unroll") for (int i = 0; i < 4; i++) {                                           \
      const bf16* p = &As[slot][mh][(wm * 64 + i * 16 + l15) * 64];                           \
      af[i][0] = *(const bf16x8*)(p + sx * 8);                                                \
      af[i][1] = *(const bf16x8*)(p + (sx ^ 4) * 8);                                          \
    }                                                                                         \
  }
#define LOAD_B(slot, nh)                                                                      \
  {                                                                                           \
    _Pragma("unroll") for (int j = 0; j < 2; j++) {                                           \
      const bf16* p = &Bs[slot][nh][(wn * 32 + j * 16 + l15) * 64];                           \
      bfr[nh][j][0] = *(const bf16x8*)(p + sx * 8);                                           \
      bfr[nh][j][1] = *(const bf16x8*)(p + (sx ^ 4) * 8);                                     \
    }                                                                                         \
  }
#define MFMA_Q(mh, nh)                                                                        \
  {                                                                                           \
    _Pragma("unroll") for (int i = 0; i < 4; i++)                                             \
        _Pragma("unroll") for (int j = 0; j < 2; j++) {                                       \
      acc[mh][i][nh][j] = MFMA16(af[i][0], bfr[nh][j][0], acc[mh][i][nh][j]);                 \
      acc[mh][i][nh][j] = MFMA16(af[i][1], bfr[nh][j][1], acc[mh][i][nh][j]);                 \
    }                                                                                         \
  }
#define BARX()                       \
  {                                  \
    asm volatile("" ::: "memory");   \
    __builtin_amdgcn_s_barrier();    \
    asm volatile("" ::: "memory");   \
  }
#define VMW(n) asm volatile("s_waitcnt vmcnt(" #n ")" ::: "memory")
#define LG0() asm volatile("s_waitcnt lgkmcnt(0)" ::: "memory")
#define NOPST {}
#define TILE_BODY(PAR, STG0, V0, STG1, V1, STG2, STG3, V3)  \
  {                                                         \
    LOAD_A(PAR, 0);                                         \
    LOAD_B(PAR, 0);                                         \
    STG0;                                                   \
    V0;                                                     \
    BARX();                                                 \
    LG0();                                                  \
    __builtin_amdgcn_s_setprio(1);                          \
    MFMA_Q(0, 0);                                           \
    __builtin_amdgcn_s_setprio(0);                          \
    BARX();                                                 \
    LOAD_B(PAR, 1);                                         \
    STG1;                                                   \
    V1;                                                     \
    BARX();                                                 \
    LG0();                                                  \
    __builtin_amdgcn_s_setprio(1);                          \
    MFMA_Q(0, 1);                                           \
    __builtin_amdgcn_s_setprio(0);                          \
    BARX();                                                 \
    LOAD_A(PAR, 1);                                         \
    STG2;                                                   \
    BARX();                                                 \
    LG0();                                                  \
    __builtin_amdgcn_s_setprio(1);                          \
    MFMA_Q(1, 0);                                           \
    __builtin_amdgcn_s_setprio(0);                          \
    BARX();                                                 \
    STG3;                                                   \
    V3;                                                     \
    BARX();                                                 \
    LG0();                                                  \
    __builtin_amdgcn_s_setprio(1);                          \
    MFMA_Q(1, 1);                                           \
    __builtin_amdgcn_s_setprio(0);                          \
    BARX();                                                 \
  }

  // prologue: issue A0(0),B0(0),B1(0),A1(0),A0(1),B0(1) = 6 half-stages (12 loads);
  // vmcnt(8) -> oldest 4 loads (A0(0),B0(0)) landed, 4 half-stages stay in flight.
  ST_A(0, 0, 0);
  ST_B(0, 0, 0);
  ST_B(0, 1, 0);
  ST_A(0, 1, 0);
  ST_A(1, 0, 1);
  ST_B(1, 0, 1);
  VMW(8);
  BARX();

#pragma unroll 1
  for (int kt = 0; kt < 14; kt += 2) {
    TILE_BODY(0, ST_B(kt + 1, 1, 1), VMW(8), ST_A(kt + 1, 1, 1), VMW(8),
              ST_A(kt + 2, 0, 0), ST_B(kt + 2, 0, 0), VMW(8));
    TILE_BODY(1, ST_B(kt + 2, 1, 0), VMW(8), ST_A(kt + 2, 1, 0), VMW(8),
              ST_A(kt + 3, 0, 1), ST_B(kt + 3, 0, 1), VMW(8));
  }
  // kt = 14 (par 0): stages tile-15 B1/A1 only; q3 waits A0(15),B0(15) -> vmcnt(4)
  TILE_BODY(0, ST_B(15, 1, 1), VMW(8), ST_A(15, 1, 1), VMW(8), NOPST, NOPST, VMW(4));
  // kt = 15 (par 1): drain — q0 needs B1(15) -> vmcnt(2); q1 needs A1(15) -> vmcnt(0)
  TILE_BODY(1, NOPST, VMW(2), NOPST, VMW(0), NOPST, NOPST, NOPST);

#undef TILE_BODY
#undef NOPST
#undef LG0
#undef VMW
#undef BARX
#undef MFMA_Q
#undef LOAD_B
#undef LOAD_A
#undef ST_B
#undef ST_A

  if (z <= 1) {
    bf16* outp = (z == 0) ? Qb : Kb;
    const float sc = (z == 0) ? 0.125f * LOG2E : 1.0f;
#pragma unroll
    for (int nh = 0; nh < 2; nh++)
#pragma unroll
      for (int j = 0; j < 2; j++) {
        const int n = nbase + nh * 128 + wn * 32 + j * 16 + l15;
        const float bv2 = bias[n];
#pragma unroll
        for (int mh = 0; mh < 2; mh++)
#pragma unroll
          for (int i = 0; i < 4; i++)
#pragma unroll
            for (int r = 0; r < 4; r++) {
              const int m = mbase + mh * 128 + wm * 64 + i * 16 + quad * 4 + r;
              outp[(size_t)m * N + n] = (bf16)((acc[mh][i][nh][j][r] + bv2) * sc);
            }
      }
  } else {
    // V: store transposed into Vt (b,h,dk,y); 4 consecutive y per fragment -> bf16x4
    const int b = mbase >> 11;
    const int y0 = mbase & 2047;
#pragma unroll
    for (int nh = 0; nh < 2; nh++)
#pragma unroll
      for (int j = 0; j < 2; j++) {
        const int n = nbase + nh * 128 + wn * 32 + j * 16 + l15;
        const float bv2 = bias[n];
        const int hh = n >> 6, dk = n & 63;
        bf16* dst0 = Vt + ((size_t)(b * H + hh) * DK + dk) * LY + y0;
#pragma unroll
        for (int mh = 0; mh < 2; mh++)
#pragma unroll
          for (int i = 0; i < 4; i++) {
            const int yy = mh * 128 + wm * 64 + i * 16 + quad * 4;
            bf16 tmp[4];
#pragma unroll
            for (int r = 0; r < 4; r++) tmp[r] = (bf16)(acc[mh][i][nh][j][r] + bv2);
            *(bf16x4*)(dst0 + yy) = *(const bf16x4*)tmp;
          }
      }
  }
}

// ---------------- out GEMM: d_out = Hb @ Wo^T + bo (f32), 128M x 64N tiles, 2 blocks/CU ----------------
__global__ __launch_bounds__(256) void out_gemm(const bf16* __restrict__ A, const bf16* __restrict__ Bt,
                                                const float* __restrict__ bias, float* __restrict__ outp) {
  constexpr int K = 1024, N = 1024;
  __shared__ __align__(16) bf16 As[128 * 64];
  __shared__ __align__(16) bf16 Bs[64 * 64];
  const int t = threadIdx.x;
  const int w = t >> 6, lane = t & 63, quad = lane >> 4, l15 = lane & 15;
  const int mbase = blockIdx.y * 128, nbase = blockIdx.x * 64;
  const int srow = lane >> 3, schunk = (lane & 7) ^ srow;
  const int sx = quad ^ (l15 & 7);

  floatx4 acc[2][4] = {};
  for (int k0 = 0; k0 < K; k0 += 64) {
    __syncthreads();
#pragma unroll
    for (int j = 0; j < 4; j++) {
      const int r0 = w * 32 + j * 8;
      cp16(A + (size_t)(mbase + r0 + srow) * K + k0 + schunk * 8, As + r0 * 64);
    }
#pragma unroll
    for (int j = 0; j < 2; j++) {
      const int r0 = w * 16 + j * 8;
      cp16(Bt + (size_t)(nbase + r0 + srow) * K + k0 + schunk * 8, Bs + r0 * 64);
    }
    __syncthreads();
    bf16x8 af[2][2], bfr[4][2];
#pragma unroll
    for (int i = 0; i < 2; i++) {
      const int ra = w * 32 + i * 16 + l15;
      af[i][0] = *(const bf16x8*)&As[ra * 64 + sx * 8];
      af[i][1] = *(const bf16x8*)&As[ra * 64 + (sx ^ 4) * 8];
    }
#pragma unroll
    for (int jn = 0; jn < 4; jn++) {
      const int rb = jn * 16 + l15;
      bfr[jn][0] = *(const bf16x8*)&Bs[rb * 64 + sx * 8];
      bfr[jn][1] = *(const bf16x8*)&Bs[rb * 64 + (sx ^ 4) * 8];
    }
#pragma unroll
    for (int i = 0; i < 2; i++)
#pragma unroll
      for (int jn = 0; jn < 4; jn++) {
        acc[i][jn] = MFMA16(af[i][0], bfr[jn][0], acc[i][jn]);
        acc[i][jn] = MFMA16(af[i][1], bfr[jn][1], acc[i][jn]);
      }
  }
#pragma unroll
  for (int jn = 0; jn < 4; jn++) {
    const int n = nbase + jn * 16 + l15;
    const float bv2 = bias[n];
#pragma unroll
    for (int i = 0; i < 2; i++)
#pragma unroll
      for (int r = 0; r < 4; r++) {
        const int m = mbase + w * 32 + i * 16 + quad * 4 + r;
        outp[(size_t)m * N + n] = acc[i][jn][r] + bv2;
      }
  }
}

// ---------------- flash attention (round-15 proven): attn9 memory schedule + deferred softmax ----------------
// Block: 128 q-rows (4 waves x 32 as 2x16 subtiles), one (b,h). Grid (16,16,2)=512 -> 2/CU.
// Memory schedule identical to attn9 (proven): 2 buffers, compile-time LDS bases,
// stage(t+1) issued in region t, tile t read in region t, 32 __syncthreads total.
// Compute deferral: region t does SCOMP(S(t)) then EXPP+PVC of tile t-1 (S held in
// s0/s1, V held in vfA/vfB across one region). Tail finishes tiles 30,31.
__global__ __launch_bounds__(256, 2) void attn12(const bf16* __restrict__ Q, const bf16* __restrict__ Kb,
                                                 const bf16* __restrict__ Vt, const float* __restrict__ mask,
                                                 const int* __restrict__ flags, bf16* __restrict__ Hout) {
  __shared__ __align__(16) bf16 Ks[2][64 * 64];
  __shared__ __align__(16) bf16 Vs[2][64 * 64];
  const int t = threadIdx.x;
  const int w = t >> 6, lane = t & 63, quad = lane >> 4, l15 = lane & 15;
  const int xt = blockIdx.x, h = blockIdx.y, b = blockIdx.z;
  const int qbase = xt * 128 + w * 32;
  const int srow = lane >> 3, schunk = (lane & 7) ^ srow;
  const int sx = quad ^ (l15 & 7);

  bf16x8 qf[2][2];
#pragma unroll
  for (int rt = 0; rt < 2; rt++) {
    const bf16* qrow = Q + (size_t)(b * LX + qbase + rt * 16 + l15) * HD + h * DK;
    qf[rt][0] = *(const bf16x8*)(qrow + quad * 8);
    qf[rt][1] = *(const bf16x8*)(qrow + 32 + quad * 8);
  }
  const int mflag = flags[b * 16 + xt];

  bf16 onearr[8];
#pragma unroll
  for (int i = 0; i < 8; i++) onearr[i] = (bf16)((l15 == 0) ? 1.0f : 0.0f);
  const bf16x8 onesf = *(const bf16x8*)onearr;

  floatx4 o[2][4] = {};
  floatx4 ol[2] = {};
  floatx4 s0[2][4], s1[2][4];
  bf16x8 kf[4][2], vfA[4][2], vfB[4][2];
  bf16x8 pf[2][2];

  const bf16* Kbase = Kb + (size_t)b * LY * HD + h * DK;
  const bf16* Vbase = Vt + (size_t)(b * H + h) * DK * LY;
  const float* mbase2 = mask + (size_t)(b * LX + qbase + l15) * LY;

#define STAGE(yt, bufi)                                                               \
  {                                                                                   \
    _Pragma("unroll") for (int j = 0; j < 2; j++) {                                   \
      const int r0 = w * 16 + j * 8;                                                  \
      cp16(Kbase + (size_t)((yt) + r0 + srow) * HD + schunk * 8, &Ks[bufi][r0 * 64]); \
      cp16(Vbase + (size_t)(r0 + srow) * LY + (yt) + schunk * 8, &Vs[bufi][r0 * 64]); \
    }                                                                                 \
  }
#define KREAD(bufi)                                                                   \
  {                                                                                   \
    const bf16* KsB = Ks[bufi];                                                       \
    _Pragma("unroll") for (int nt = 0; nt < 4; nt++) {                                \
      const int ry = nt * 16 + l15;                                                   \
      kf[nt][0] = *(const bf16x8*)&KsB[ry * 64 + sx * 8];                             \
      kf[nt][1] = *(const bf16x8*)&KsB[ry * 64 + (sx ^ 4) * 8];                       \
    }                                                                                 \
  }
#define VREAD(bufi, VF)                                                               \
  {                                                                                   \
    const bf16* VsB = Vs[bufi];                                                       \
    _Pragma("unroll") for (int u = 0; u < 4; u++) {                                   \
      const int rd = u * 16 + l15;                                                    \
      VF[u][0] = *(const bf16x8*)&VsB[rd * 64 + sx * 8];                              \
      VF[u][1] = *(const bf16x8*)&VsB[rd * 64 + (sx ^ 4) * 8];                        \
    }                                                                                 \
  }
#define SCOMP(SD)                                                                     \
  {                                                                                   \
    __builtin_amdgcn_s_setprio(1);                                                    \
    _Pragma("unroll") for (int nt = 0; nt < 4; nt++)                                  \
        _Pragma("unroll") for (int rt = 0; rt < 2; rt++) {                            \
      floatx4 sz = {0.f, 0.f, 0.f, 0.f};                                              \
      sz = MFMA16(kf[nt][0], qf[rt][0], sz);                                          \
      SD[rt][nt] = MFMA16(kf[nt][1], qf[rt][1], sz);                                  \
    }                                                                                 \
    __builtin_amdgcn_s_setprio(0);                                                    \
  }
#define EXPP(SS, yt)                                                                  \
  {                                                                                   \
    if (mflag) {                                                                      \
      _Pragma("unroll") for (int rt = 0; rt < 2; rt++)                                \
          _Pragma("unroll") for (int nt = 0; nt < 4; nt++) {                          \
        const float* mp = mbase2 + (size_t)rt * 16 * LY + (yt) + nt * 16 + quad * 4;  \
        float4 mv = *(const float4*)mp;                                               \
        SS[rt][nt][0] = fminf(SS[rt][nt][0] + LOG2E * mv.x, 30.f);                    \
        SS[rt][nt][1] = fminf(SS[rt][nt][1] + LOG2E * mv.y, 30.f);                    \
        SS[rt][nt][2] = fminf(SS[rt][nt][2] + LOG2E * mv.z, 30.f);                    \
        SS[rt][nt][3] = fminf(SS[rt][nt][3] + LOG2E * mv.w, 30.f);                    \
      }                                                                               \
    }                                                                                 \
    _Pragma("unroll") for (int rt = 0; rt < 2; rt++) {                                \
      uintx4 wd0, wd1;                                                                \
      _Pragma("unroll") for (int F = 0; F < 2; F++)                                   \
          _Pragma("unroll") for (int hh = 0; hh < 2; hh++) {                          \
        unsigned wa = pk2(__builtin_amdgcn_exp2f(SS[rt][2 * F][2 * hh]),              \
                          __builtin_amdgcn_exp2f(SS[rt][2 * F][2 * hh + 1]));         \
        unsigned wb = pk2(__builtin_amdgcn_exp2f(SS[rt][2 * F + 1][2 * hh]),          \
                          __builtin_amdgcn_exp2f(SS[rt][2 * F + 1][2 * hh + 1]));     \
        asm("v_permlane32_swap_b32 %0, %1" : "+v"(wa), "+v"(wb));                     \
        asm("v_permlane16_swap_b32 %0, %1" : "+v"(wa), "+v"(wb));                     \
        if (F == 0) {                                                                 \
          wd0[hh] = wa;                                                               \
          wd0[hh + 2] = wb;                                                           \
        } else {                                                                      \
          wd1[hh] = wa;                                                               \
          wd1[hh + 2] = wb;                                                           \
        }                                                                             \
      }                                                                               \
      pf[rt][0] = __builtin_bit_cast(bf16x8, wd0);                                    \
      pf[rt][1] = __builtin_bit_cast(bf16x8, wd1);                                    \
    }                                                                                 \
  }
#define PVC(VF)                                                                       \
  {                                                                                   \
    __builtin_amdgcn_s_setprio(1);                                                    \
    _Pragma("unroll") for (int u = 0; u < 4; u++) {                                   \
      _Pragma("unroll") for (int rt = 0; rt < 2; rt++) {                              \
        o[rt][u] = MFMA16(pf[rt][0], VF[u][0], o[rt][u]);                             \
        o[rt][u] = MFMA16(pf[rt][1], VF[u][1], o[rt][u]);                             \
      }                                                                               \
    }                                                                                 \
    _Pragma("unroll") for (int rt = 0; rt < 2; rt++) {                                \
      ol[rt] = MFMA16(pf[rt][0], onesf, ol[rt]);                                      \
      ol[rt] = MFMA16(pf[rt][1], onesf, ol[rt]);                                      \
    }                                                                                 \
    __builtin_amdgcn_s_setprio(0);                                                    \
  }

  // region 0: tile 0 (buf0); stage tile 1 (buf1).
  STAGE(0, 0);
  __syncthreads();
  STAGE(64, 1);
  KREAD(0);
  SCOMP(s0);
  VREAD(0, vfA);

  // regions 1..30: region i computes S(i), finishes tile i-1.
#pragma unroll 1
  for (int i = 1; i < 31; i += 2) {
    // region i (odd tile -> buf1)
    __syncthreads();
    STAGE((i + 1) * 64, 0);
    KREAD(1);
    SCOMP(s1);
    VREAD(1, vfB);
    EXPP(s0, (i - 1) * 64);
    PVC(vfA);
    // region i+1 (even tile -> buf0)
    __syncthreads();
    if (i + 2 < 32) STAGE((i + 2) * 64, 1);
    KREAD(0);
    SCOMP(s0);
    VREAD(0, vfA);
    EXPP(s1, i * 64);
    PVC(vfB);
  }
  // region 31: tile 31 (buf1); finish tile 30, then tail-finish tile 31.
  __syncthreads();
  KREAD(1);
  SCOMP(s1);
  VREAD(1, vfB);
  EXPP(s0, 30 * 64);
  PVC(vfA);
  EXPP(s1, 31 * 64);
  PVC(vfB);

#pragma unroll
  for (int rt = 0; rt < 2; rt++)
#pragma unroll
    for (int r = 0; r < 4; r++) {
      const float lsum = __shfl(ol[rt][r], lane & 48, 64);
      const float rl = 1.0f / lsum;
      const int m = b * LX + qbase + rt * 16 + quad * 4 + r;
#pragma unroll
      for (int u = 0; u < 4; u++)
        Hout[(size_t)m * HD + h * DK + u * 16 + l15] = (bf16)(o[rt][u][r] * rl);
    }
#undef STAGE
#undef KREAD
#undef VREAD
#undef SCOMP
#undef EXPP
#undef PVC
}

// ---------------- launch ----------------
extern "C" void kernel_launch(void* const* d_in, const int* in_sizes, int n_in,
                              void* d_out, int out_size, void* d_ws, size_t ws_size,
                              hipStream_t stream) {
  const float* x = (const float*)d_in[0];
  const float* y = (const float*)d_in[1];
  const float* mask = (const float*)d_in[2];
  const float* Wq = (const float*)d_in[3];
  const float* bq = (const float*)d_in[4];
  const float* Wk = (const float*)d_in[5];
  const float* bk = (const float*)d_in[6];
  const float* Wv = (const float*)d_in[7];
  const float* bv = (const float*)d_in[8];
  const float* Wo = (const float*)d_in[9];
  const float* bo = (const float*)d_in[10];

  char* ws = (char*)d_ws;
  size_t off = 0;
  int* flags = (int*)(ws + off); off += 256;
  bf16* Qb = (bf16*)(ws + off); off += (size_t)BS * LX * HD * 2;
  bf16* Kb = (bf16*)(ws + off); off += (size_t)BS * LY * HD * 2;
  bf16* Vt = (bf16*)(ws + off); off += (size_t)BS * LY * HD * 2;  // (b,h,dk,y)
  bf16* Hb = (bf16*)(ws + off); off += (size_t)BS * LX * HD * 2;
  bf16* xbf = (bf16*)(ws + off); off += (size_t)BS * LX * D * 2;
  bf16* ybf = (bf16*)(ws + off); off += (size_t)BS * LY * D * 2;
  bf16* Wtq = (bf16*)(ws + off); off += (size_t)D * HD * 2;
  bf16* Wtk = (bf16*)(ws + off); off += (size_t)D * HD * 2;
  bf16* Wtv = (bf16*)(ws + off); off += (size_t)D * HD * 2;
  bf16* Wto = (bf16*)(ws + off); off += (size_t)HD * D * 2;

  dim3 blk(256);
  hipMemsetAsync(flags, 0, 32 * sizeof(int), stream);
  prep<<<dim3(6144), blk, 0, stream>>>(Wq, Wtq, Wk, Wtk, Wv, Wtv, Wo, Wto, x, xbf, y, ybf, mask, flags);
  qkv8<<<dim3(4, 16, 3), dim3(512), 0, stream>>>(xbf, ybf, Wtq, Wtk, Wtv, bq, bk, bv, Qb, Kb, Vt);
  attn12<<<dim3(16, 16, 2), blk, 0, stream>>>(Qb, Kb, Vt, mask, flags, Hb);
  out_gemm<<<dim3(16, 32), blk, 0, stream>>>(Hb, Wto, bo, (float*)d_out);
}

// Round 14
// 222.655 us; speedup vs baseline: 1.1233x; 1.0013x over previous
//
#include <hip/hip_runtime.h>
#include <hip/hip_bf16.h>

// EditOuterAttention — round 23.
// out = softmax((x Wq + bq)(y Wk + bk)^T / 8 + mask) (y Wv + bv) Wo + bo
// BS=2, LX=LY=2048, D=1024, H=16, DK=64.
//
// Round-23 delta (on the 222.94us session-best config):
//  - attn12 -> attn12s: XCD-aware block swizzle (T1). FETCH 69.7MB vs ~24MB ideal ->
//    K/V of each (b,h) replicated across all 8 XCD L2s by the default x-fastest
//    dispatch. 1D grid 512, flat=(g>>3)*128+xt*8+(g&7) (bijective): all 16 xt-blocks
//    of a (b,h) -> same XCD; 4 groups x 512KB = 2MB/XCD, fits 4MB L2. Kernel body
//    byte-identical. If null/negative: plateau confirmed, round-22 config is final.
//  - prep / qkv8 / out_gemm unchanged.

typedef __bf16 bf16;
typedef __bf16 bf16x2 __attribute__((ext_vector_type(2)));
typedef __bf16 bf16x4 __attribute__((ext_vector_type(4)));
typedef __bf16 bf16x8 __attribute__((ext_vector_type(8)));
typedef float floatx4 __attribute__((ext_vector_type(4)));
typedef unsigned int uintx4 __attribute__((ext_vector_type(4)));

#define MFMA16(a, b, c) __builtin_amdgcn_mfma_f32_16x16x32_bf16(a, b, c, 0, 0, 0)

constexpr int BS = 2, LX = 2048, LY = 2048, D = 1024, H = 16, DK = 64;
constexpr int HD = H * DK;  // 1024
constexpr float LOG2E = 1.4426950408889634f;

__device__ __forceinline__ void cp16(const bf16* g, bf16* l) {
  __builtin_amdgcn_global_load_lds(
      (const __attribute__((address_space(1))) unsigned int*)g,
      (__attribute__((address_space(3))) unsigned int*)l, 16, 0, 0);
}

__device__ __forceinline__ unsigned pk2(float a, float b) {
  bf16x2 p;
  p[0] = (bf16)a;
  p[1] = (bf16)b;
  return __builtin_bit_cast(unsigned, p);
}

// ---------------- fused prep: weight transpose x4 | x,y bf16 convert | mask scan ----------------
__global__ __launch_bounds__(256) void prep(const float* __restrict__ W0, bf16* __restrict__ T0,
                                            const float* __restrict__ W1, bf16* __restrict__ T1,
                                            const float* __restrict__ W2, bf16* __restrict__ T2,
                                            const float* __restrict__ W3, bf16* __restrict__ T3,
                                            const float* __restrict__ x, bf16* __restrict__ xb,
                                            const float* __restrict__ y, bf16* __restrict__ yb,
                                            const float* __restrict__ mask, int* __restrict__ flags) {
  const int id = blockIdx.x;
  const int t = threadIdx.x;
  if (id < 1024) {
    __shared__ bf16 tile[64][72];
    const float* W;
    bf16* T;
    switch (id >> 8) {
      case 0: W = W0; T = T0; break;
      case 1: W = W1; T = T1; break;
      case 2: W = W2; T = T2; break;
      default: W = W3; T = T3; break;
    }
    const int kt = id & 15, nt = (id >> 4) & 15;
    const int r = t >> 2, c4 = (t & 3) * 16;
    const float* src = W + (size_t)(kt * 64 + r) * 1024 + nt * 64 + c4;
#pragma unroll
    for (int i = 0; i < 16; i++) tile[r][c4 + i] = (bf16)src[i];
    __syncthreads();
    bf16 vals[16];
#pragma unroll
    for (int i = 0; i < 16; i++) vals[i] = tile[c4 + i][r];
    bf16* dst = T + (size_t)(nt * 64 + r) * 1024 + kt * 64 + c4;
#pragma unroll
    for (int i = 0; i < 16; i++) dst[i] = vals[i];
  } else if (id < 5120) {
    const int id2 = id - 1024;
    const float* src = (id2 >= 2048) ? y : x;
    bf16* dst = (id2 >= 2048) ? yb : xb;
    const size_t i = ((size_t)(id2 & 2047) * 256 + t) * 8;
    float4 a = *(const float4*)(src + i);
    float4 c = *(const float4*)(src + i + 4);
    bf16 tmp[8] = {(bf16)a.x, (bf16)a.y, (bf16)a.z, (bf16)a.w,
                   (bf16)c.x, (bf16)c.y, (bf16)c.z, (bf16)c.w};
    *(bf16x8*)(dst + i) = *(const bf16x8*)tmp;
  } else {
    const int id3 = id - 5120;
    const int region = id3 >> 5, sub = id3 & 31;
    const float4* p = (const float4*)mask + (size_t)region * 65536 + sub * 2048;
    bool nz = false;
#pragma unroll
    for (int it = 0; it < 8; it++) {
      float4 v = p[it * 256 + t];
      nz |= (v.x != 0.f) | (v.y != 0.f) | (v.z != 0.f) | (v.w != 0.f);
    }
    if (nz) atomicOr(&flags[region], 1);
  }
}

// ---------------- fused QKV projection GEMM: 256^2 tile, BK=64, counted-vmcnt 4-phase ----------------
__global__ __launch_bounds__(512, 2) void qkv8(const bf16* __restrict__ xb, const bf16* __restrict__ yb,
                                               const bf16* __restrict__ Wtq, const bf16* __restrict__ Wtk,
                                               const bf16* __restrict__ Wtv,
                                               const float* __restrict__ bq, const float* __restrict__ bk,
                                               const float* __restrict__ bv,
                                               bf16* __restrict__ Qb, bf16* __restrict__ Kb,
                                               bf16* __restrict__ Vt) {
  constexpr int K = 1024, N = 1024;
  __shared__ __align__(16) bf16 As[2][2][128 * 64];  // [tile-parity][half][row*64+k]
  __shared__ __align__(16) bf16 Bs[2][2][128 * 64];

  const int z = blockIdx.z;
  const bf16* A = (z == 0) ? xb : yb;
  const bf16* Bt = (z == 0) ? Wtq : (z == 1) ? Wtk : Wtv;
  const float* bias = (z == 0) ? bq : (z == 1) ? bk : bv;

  const int t = threadIdx.x;
  const int w = t >> 6, lane = t & 63, quad = lane >> 4, l15 = lane & 15;
  const int wm = w >> 2, wn = w & 3;
  const int mbase = blockIdx.y * 256, nbase = blockIdx.x * 256;
  const int srow = lane >> 3, schunk = (lane & 7) ^ srow;
  const int sx = quad ^ (l15 & 7);

  floatx4 acc[2][4][2][2] = {};
  bf16x8 af[4][2];
  bf16x8 bfr[2][2][2];

#define ST_A(ktt, half, slot)                                                                 \
  {                                                                                           \
    _Pragma("unroll") for (int j = 0; j < 2; j++) {                                           \
      const int r0 = w * 16 + j * 8;                                                          \
      cp16(A + (size_t)(mbase + (half) * 128 + r0 + srow) * K + (ktt) * 64 + schunk * 8,      \
           &As[slot][half][r0 * 64]);                                                         \
    }                                                                                         \
  }
#define ST_B(ktt, half, slot)                                                                 \
  {                                                                                           \
    _Pragma("unroll") for (int j = 0; j < 2; j++) {                                           \
      const int r0 = w * 16 + j * 8;                                                          \
      cp16(Bt + (size_t)(nbase + (half) * 128 + r0 + srow) * K + (ktt) * 64 + schunk * 8,     \
           &Bs[slot][half][r0 * 64]);                                                         \
    }                                                                                         \
  }
#define LOAD_A(slot, mh)                                                                      \
  {                                                                                           \
    _Pragma("unroll") for (int i = 0; i < 4; i++) {                                           \
      const bf16* p = &As[slot][mh][(wm * 64 + i * 16 + l15) * 64];                           \
      af[i][0] = *(const bf16x8*)(p + sx * 8);                                                \
      af[i][1] = *(const bf16x8*)(p + (sx ^ 4) * 8);                                          \
    }                                                                                         \
  }
#define LOAD_B(slot, nh)                                                                      \
  {                                                                                           \
    _Pragma("unroll") for (int j = 0; j < 2; j++) {                                           \
      const bf16* p = &Bs[slot][nh][(wn * 32 + j * 16 + l15) * 64];                           \
      bfr[nh][j][0] = *(const bf16x8*)(p + sx * 8);                                           \
      bfr[nh][j][1] = *(const bf16x8*)(p + (sx ^ 4) * 8);                                     \
    }                                                                                         \
  }
#define MFMA_Q(mh, nh)                                                                        \
  {                                                                                           \
    _Pragma("unroll") for (int i = 0; i < 4; i++)                                             \
        _Pragma("unroll") for (int j = 0; j < 2; j++) {                                       \
      acc[mh][i][nh][j] = MFMA16(af[i][0], bfr[nh][j][0], acc[mh][i][nh][j]);                 \
      acc[mh][i][nh][j] = MFMA16(af[i][1], bfr[nh][j][1], acc[mh][i][nh][j]);                 \
    }                                                                                         \
  }
#define BARX()                       \
  {                                  \
    asm volatile("" ::: "memory");   \
    __builtin_amdgcn_s_barrier();    \
    asm volatile("" ::: "memory");   \
  }
#define VMW(n) asm volatile("s_waitcnt vmcnt(" #n ")" ::: "memory")
#define LG0() asm volatile("s_waitcnt lgkmcnt(0)" ::: "memory")
#define NOPST {}
#define TILE_BODY(PAR, STG0, V0, STG1, V1, STG2, STG3, V3)  \
  {                                                         \
    LOAD_A(PAR, 0);                                         \
    LOAD_B(PAR, 0);                                         \
    STG0;                                                   \
    V0;                                                     \
    BARX();                                                 \
    LG0();                                                  \
    __builtin_amdgcn_s_setprio(1);                          \
    MFMA_Q(0, 0);                                           \
    __builtin_amdgcn_s_setprio(0);                          \
    BARX();                                                 \
    LOAD_B(PAR, 1);                                         \
    STG1;                                                   \
    V1;                                                     \
    BARX();                                                 \
    LG0();                                                  \
    __builtin_amdgcn_s_setprio(1);                          \
    MFMA_Q(0, 1);                                           \
    __builtin_amdgcn_s_setprio(0);                          \
    BARX();                                                 \
    LOAD_A(PAR, 1);                                         \
    STG2;                                                   \
    BARX();                                                 \
    LG0();                                                  \
    __builtin_amdgcn_s_setprio(1);                          \
    MFMA_Q(1, 0);                                           \
    __builtin_amdgcn_s_setprio(0);                          \
    BARX();                                                 \
    STG3;                                                   \
    V3;                                                     \
    BARX();                                                 \
    LG0();                                                  \
    __builtin_amdgcn_s_setprio(1);                          \
    MFMA_Q(1, 1);                                           \
    __builtin_amdgcn_s_setprio(0);                          \
    BARX();                                                 \
  }

  // prologue: issue A0(0),B0(0),B1(0),A1(0),A0(1),B0(1) = 6 half-stages (12 loads);
  // vmcnt(8) -> oldest 4 loads (A0(0),B0(0)) landed, 4 half-stages stay in flight.
  ST_A(0, 0, 0);
  ST_B(0, 0, 0);
  ST_B(0, 1, 0);
  ST_A(0, 1, 0);
  ST_A(1, 0, 1);
  ST_B(1, 0, 1);
  VMW(8);
  BARX();

#pragma unroll 1
  for (int kt = 0; kt < 14; kt += 2) {
    TILE_BODY(0, ST_B(kt + 1, 1, 1), VMW(8), ST_A(kt + 1, 1, 1), VMW(8),
              ST_A(kt + 2, 0, 0), ST_B(kt + 2, 0, 0), VMW(8));
    TILE_BODY(1, ST_B(kt + 2, 1, 0), VMW(8), ST_A(kt + 2, 1, 0), VMW(8),
              ST_A(kt + 3, 0, 1), ST_B(kt + 3, 0, 1), VMW(8));
  }
  // kt = 14 (par 0): stages tile-15 B1/A1 only; q3 waits A0(15),B0(15) -> vmcnt(4)
  TILE_BODY(0, ST_B(15, 1, 1), VMW(8), ST_A(15, 1, 1), VMW(8), NOPST, NOPST, VMW(4));
  // kt = 15 (par 1): drain — q0 needs B1(15) -> vmcnt(2); q1 needs A1(15) -> vmcnt(0)
  TILE_BODY(1, NOPST, VMW(2), NOPST, VMW(0), NOPST, NOPST, NOPST);

#undef TILE_BODY
#undef NOPST
#undef LG0
#undef VMW
#undef BARX
#undef MFMA_Q
#undef LOAD_B
#undef LOAD_A
#undef ST_B
#undef ST_A

  if (z <= 1) {
    bf16* outp = (z == 0) ? Qb : Kb;
    const float sc = (z == 0) ? 0.125f * LOG2E : 1.0f;
#pragma unroll
    for (int nh = 0; nh < 2; nh++)
#pragma unroll
      for (int j = 0; j < 2; j++) {
        const int n = nbase + nh * 128 + wn * 32 + j * 16 + l15;
        const float bv2 = bias[n];
#pragma unroll
        for (int mh = 0; mh < 2; mh++)
#pragma unroll
          for (int i = 0; i < 4; i++)
#pragma unroll
            for (int r = 0; r < 4; r++) {
              const int m = mbase + mh * 128 + wm * 64 + i * 16 + quad * 4 + r;
              outp[(size_t)m * N + n] = (bf16)((acc[mh][i][nh][j][r] + bv2) * sc);
            }
      }
  } else {
    // V: store transposed into Vt (b,h,dk,y); 4 consecutive y per fragment -> bf16x4
    const int b = mbase >> 11;
    const int y0 = mbase & 2047;
#pragma unroll
    for (int nh = 0; nh < 2; nh++)
#pragma unroll
      for (int j = 0; j < 2; j++) {
        const int n = nbase + nh * 128 + wn * 32 + j * 16 + l15;
        const float bv2 = bias[n];
        const int hh = n >> 6, dk = n & 63;
        bf16* dst0 = Vt + ((size_t)(b * H + hh) * DK + dk) * LY + y0;
#pragma unroll
        for (int mh = 0; mh < 2; mh++)
#pragma unroll
          for (int i = 0; i < 4; i++) {
            const int yy = mh * 128 + wm * 64 + i * 16 + quad * 4;
            bf16 tmp[4];
#pragma unroll
            for (int r = 0; r < 4; r++) tmp[r] = (bf16)(acc[mh][i][nh][j][r] + bv2);
            *(bf16x4*)(dst0 + yy) = *(const bf16x4*)tmp;
          }
      }
  }
}

// ---------------- out GEMM: d_out = Hb @ Wo^T + bo (f32), 128M x 64N tiles, 2 blocks/CU ----------------
__global__ __launch_bounds__(256) void out_gemm(const bf16* __restrict__ A, const bf16* __restrict__ Bt,
                                                const float* __restrict__ bias, float* __restrict__ outp) {
  constexpr int K = 1024, N = 1024;
  __shared__ __align__(16) bf16 As[128 * 64];
  __shared__ __align__(16) bf16 Bs[64 * 64];
  const int t = threadIdx.x;
  const int w = t >> 6, lane = t & 63, quad = lane >> 4, l15 = lane & 15;
  const int mbase = blockIdx.y * 128, nbase = blockIdx.x * 64;
  const int srow = lane >> 3, schunk = (lane & 7) ^ srow;
  const int sx = quad ^ (l15 & 7);

  floatx4 acc[2][4] = {};
  for (int k0 = 0; k0 < K; k0 += 64) {
    __syncthreads();
#pragma unroll
    for (int j = 0; j < 4; j++) {
      const int r0 = w * 32 + j * 8;
      cp16(A + (size_t)(mbase + r0 + srow) * K + k0 + schunk * 8, As + r0 * 64);
    }
#pragma unroll
    for (int j = 0; j < 2; j++) {
      const int r0 = w * 16 + j * 8;
      cp16(Bt + (size_t)(nbase + r0 + srow) * K + k0 + schunk * 8, Bs + r0 * 64);
    }
    __syncthreads();
    bf16x8 af[2][2], bfr[4][2];
#pragma unroll
    for (int i = 0; i < 2; i++) {
      const int ra = w * 32 + i * 16 + l15;
      af[i][0] = *(const bf16x8*)&As[ra * 64 + sx * 8];
      af[i][1] = *(const bf16x8*)&As[ra * 64 + (sx ^ 4) * 8];
    }
#pragma unroll
    for (int jn = 0; jn < 4; jn++) {
      const int rb = jn * 16 + l15;
      bfr[jn][0] = *(const bf16x8*)&Bs[rb * 64 + sx * 8];
      bfr[jn][1] = *(const bf16x8*)&Bs[rb * 64 + (sx ^ 4) * 8];
    }
#pragma unroll
    for (int i = 0; i < 2; i++)
#pragma unroll
      for (int jn = 0; jn < 4; jn++) {
        acc[i][jn] = MFMA16(af[i][0], bfr[jn][0], acc[i][jn]);
        acc[i][jn] = MFMA16(af[i][1], bfr[jn][1], acc[i][jn]);
      }
  }
#pragma unroll
  for (int jn = 0; jn < 4; jn++) {
    const int n = nbase + jn * 16 + l15;
    const float bv2 = bias[n];
#pragma unroll
    for (int i = 0; i < 2; i++)
#pragma unroll
      for (int r = 0; r < 4; r++) {
        const int m = mbase + w * 32 + i * 16 + quad * 4 + r;
        outp[(size_t)m * N + n] = acc[i][jn][r] + bv2;
      }
  }
}

// ---------------- flash attention: deferred softmax + XCD-aware block swizzle ----------------
// Block: 128 q-rows (4 waves x 32 as 2x16 subtiles), one (b,h). 1D grid 512:
// flat = (g>>3)*128 + xt*8 + (g&7), g = b*16+h -> all 16 xt of a (b,h) share an XCD
// (4 groups x 512KB K/V = 2MB per XCD L2). Body identical to round-22 attn12.
__global__ __launch_bounds__(256, 2) void attn12s(const bf16* __restrict__ Q, const bf16* __restrict__ Kb,
                                                  const bf16* __restrict__ Vt, const float* __restrict__ mask,
                                                  const int* __restrict__ flags, bf16* __restrict__ Hout) {
  __shared__ __align__(16) bf16 Ks[2][64 * 64];
  __shared__ __align__(16) bf16 Vs[2][64 * 64];
  const int t = threadIdx.x;
  const int w = t >> 6, lane = t & 63, quad = lane >> 4, l15 = lane & 15;
  const int flat = blockIdx.x;
  const int gg = (flat & 7) | ((flat >> 7) << 3);  // group = b*16+h
  const int xt = (flat >> 3) & 15;
  const int h = gg & 15, b = gg >> 4;
  const int qbase = xt * 128 + w * 32;
  const int srow = lane >> 3, schunk = (lane & 7) ^ srow;
  const int sx = quad ^ (l15 & 7);

  bf16x8 qf[2][2];
#pragma unroll
  for (int rt = 0; rt < 2; rt++) {
    const bf16* qrow = Q + (size_t)(b * LX + qbase + rt * 16 + l15) * HD + h * DK;
    qf[rt][0] = *(const bf16x8*)(qrow + quad * 8);
    qf[rt][1] = *(const bf16x8*)(qrow + 32 + quad * 8);
  }
  const int mflag = flags[b * 16 + xt];

  bf16 onearr[8];
#pragma unroll
  for (int i = 0; i < 8; i++) onearr[i] = (bf16)((l15 == 0) ? 1.0f : 0.0f);
  const bf16x8 onesf = *(const bf16x8*)onearr;

  floatx4 o[2][4] = {};
  floatx4 ol[2] = {};
  floatx4 s0[2][4], s1[2][4];
  bf16x8 kf[4][2], vfA[4][2], vfB[4][2];
  bf16x8 pf[2][2];

  const bf16* Kbase = Kb + (size_t)b * LY * HD + h * DK;
  const bf16* Vbase = Vt + (size_t)(b * H + h) * DK * LY;
  const float* mbase2 = mask + (size_t)(b * LX + qbase + l15) * LY;

#define STAGE(yt, bufi)                                                               \
  {                                                                                   \
    _Pragma("unroll") for (int j = 0; j < 2; j++) {                                   \
      const int r0 = w * 16 + j * 8;                                                  \
      cp16(Kbase + (size_t)((yt) + r0 + srow) * HD + schunk * 8, &Ks[bufi][r0 * 64]); \
      cp16(Vbase + (size_t)(r0 + srow) * LY + (yt) + schunk * 8, &Vs[bufi][r0 * 64]); \
    }                                                                                 \
  }
#define KREAD(bufi)                                                                   \
  {                                                                                   \
    const bf16* KsB = Ks[bufi];                                                       \
    _Pragma("unroll") for (int nt = 0; nt < 4; nt++) {                                \
      const int ry = nt * 16 + l15;                                                   \
      kf[nt][0] = *(const bf16x8*)&KsB[ry * 64 + sx * 8];                             \
      kf[nt][1] = *(const bf16x8*)&KsB[ry * 64 + (sx ^ 4) * 8];                       \
    }                                                                                 \
  }
#define VREAD(bufi, VF)                                                               \
  {                                                                                   \
    const bf16* VsB = Vs[bufi];                                                       \
    _Pragma("unroll") for (int u = 0; u < 4; u++) {                                   \
      const int rd = u * 16 + l15;                                                    \
      VF[u][0] = *(const bf16x8*)&VsB[rd * 64 + sx * 8];                              \
      VF[u][1] = *(const bf16x8*)&VsB[rd * 64 + (sx ^ 4) * 8];                        \
    }                                                                                 \
  }
#define SCOMP(SD)                                                                     \
  {                                                                                   \
    __builtin_amdgcn_s_setprio(1);                                                    \
    _Pragma("unroll") for (int nt = 0; nt < 4; nt++)                                  \
        _Pragma("unroll") for (int rt = 0; rt < 2; rt++) {                            \
      floatx4 sz = {0.f, 0.f, 0.f, 0.f};                                              \
      sz = MFMA16(kf[nt][0], qf[rt][0], sz);                                          \
      SD[rt][nt] = MFMA16(kf[nt][1], qf[rt][1], sz);                                  \
    }                                                                                 \
    __builtin_amdgcn_s_setprio(0);                                                    \
  }
#define EXPP(SS, yt)                                                                  \
  {                                                                                   \
    if (mflag) {                                                                      \
      _Pragma("unroll") for (int rt = 0; rt < 2; rt++)                                \
          _Pragma("unroll") for (int nt = 0; nt < 4; nt++) {                          \
        const float* mp = mbase2 + (size_t)rt * 16 * LY + (yt) + nt * 16 + quad * 4;  \
        float4 mv = *(const float4*)mp;                                               \
        SS[rt][nt][0] = fminf(SS[rt][nt][0] + LOG2E * mv.x, 30.f);                    \
        SS[rt][nt][1] = fminf(SS[rt][nt][1] + LOG2E * mv.y, 30.f);                    \
        SS[rt][nt][2] = fminf(SS[rt][nt][2] + LOG2E * mv.z, 30.f);                    \
        SS[rt][nt][3] = fminf(SS[rt][nt][3] + LOG2E * mv.w, 30.f);                    \
      }                                                                               \
    }                                                                                 \
    _Pragma("unroll") for (int rt = 0; rt < 2; rt++) {                                \
      uintx4 wd0, wd1;                                                                \
      _Pragma("unroll") for (int F = 0; F < 2; F++)                                   \
          _Pragma("unroll") for (int hh = 0; hh < 2; hh++) {                          \
        unsigned wa = pk2(__builtin_amdgcn_exp2f(SS[rt][2 * F][2 * hh]),              \
                          __builtin_amdgcn_exp2f(SS[rt][2 * F][2 * hh + 1]));         \
        unsigned wb = pk2(__builtin_amdgcn_exp2f(SS[rt][2 * F + 1][2 * hh]),          \
                          __builtin_amdgcn_exp2f(SS[rt][2 * F + 1][2 * hh + 1]));     \
        asm("v_permlane32_swap_b32 %0, %1" : "+v"(wa), "+v"(wb));                     \
        asm("v_permlane16_swap_b32 %0, %1" : "+v"(wa), "+v"(wb));                     \
        if (F == 0) {                                                                 \
          wd0[hh] = wa;                                                               \
          wd0[hh + 2] = wb;                                                           \
        } else {                                                                      \
          wd1[hh] = wa;                                                               \
          wd1[hh + 2] = wb;                                                           \
        }                                                                             \
      }                                                                               \
      pf[rt][0] = __builtin_bit_cast(bf16x8, wd0);                                    \
      pf[rt][1] = __builtin_bit_cast(bf16x8, wd1);                                    \
    }                                                                                 \
  }
#define PVC(VF)                                                                       \
  {                                                                                   \
    __builtin_amdgcn_s_setprio(1);                                                    \
    _Pragma("unroll") for (int u = 0; u < 4; u++) {                                   \
      _Pragma("unroll") for (int rt = 0; rt < 2; rt++) {                              \
        o[rt][u] = MFMA16(pf[rt][0], VF[u][0], o[rt][u]);                             \
        o[rt][u] = MFMA16(pf[rt][1], VF[u][1], o[rt][u]);                             \
      }                                                                               \
    }                                                                                 \
    _Pragma("unroll") for (int rt = 0; rt < 2; rt++) {                                \
      ol[rt] = MFMA16(pf[rt][0], onesf, ol[rt]);                                      \
      ol[rt] = MFMA16(pf[rt][1], onesf, ol[rt]);                                      \
    }                                                                                 \
    __builtin_amdgcn_s_setprio(0);                                                    \
  }

  // region 0: tile 0 (buf0); stage tile 1 (buf1).
  STAGE(0, 0);
  __syncthreads();
  STAGE(64, 1);
  KREAD(0);
  SCOMP(s0);
  VREAD(0, vfA);

  // regions 1..30: region i computes S(i), finishes tile i-1.
#pragma unroll 1
  for (int i = 1; i < 31; i += 2) {
    // region i (odd tile -> buf1)
    __syncthreads();
    STAGE((i + 1) * 64, 0);
    KREAD(1);
    SCOMP(s1);
    VREAD(1, vfB);
    EXPP(s0, (i - 1) * 64);
    PVC(vfA);
    // region i+1 (even tile -> buf0)
    __syncthreads();
    if (i + 2 < 32) STAGE((i + 2) * 64, 1);
    KREAD(0);
    SCOMP(s0);
    VREAD(0, vfA);
    EXPP(s1, i * 64);
    PVC(vfB);
  }
  // region 31: tile 31 (buf1); finish tile 30, then tail-finish tile 31.
  __syncthreads();
  KREAD(1);
  SCOMP(s1);
  VREAD(1, vfB);
  EXPP(s0, 30 * 64);
  PVC(vfA);
  EXPP(s1, 31 * 64);
  PVC(vfB);

#pragma unroll
  for (int rt = 0; rt < 2; rt++)
#pragma unroll
    for (int r = 0; r < 4; r++) {
      const float lsum = __shfl(ol[rt][r], lane & 48, 64);
      const float rl = 1.0f / lsum;
      const int m = b * LX + qbase + rt * 16 + quad * 4 + r;
#pragma unroll
      for (int u = 0; u < 4; u++)
        Hout[(size_t)m * HD + h * DK + u * 16 + l15] = (bf16)(o[rt][u][r] * rl);
    }
#undef STAGE
#undef KREAD
#undef VREAD
#undef SCOMP
#undef EXPP
#undef PVC
}

// ---------------- launch ----------------
extern "C" void kernel_launch(void* const* d_in, const int* in_sizes, int n_in,
                              void* d_out, int out_size, void* d_ws, size_t ws_size,
                              hipStream_t stream) {
  const float* x = (const float*)d_in[0];
  const float* y = (const float*)d_in[1];
  const float* mask = (const float*)d_in[2];
  const float* Wq = (const float*)d_in[3];
  const float* bq = (const float*)d_in[4];
  const float* Wk = (const float*)d_in[5];
  const float* bk = (const float*)d_in[6];
  const float* Wv = (const float*)d_in[7];
  const float* bv = (const float*)d_in[8];
  const float* Wo = (const float*)d_in[9];
  const float* bo = (const float*)d_in[10];

  char* ws = (char*)d_ws;
  size_t off = 0;
  int* flags = (int*)(ws + off); off += 256;
  bf16* Qb = (bf16*)(ws + off); off += (size_t)BS * LX * HD * 2;
  bf16* Kb = (bf16*)(ws + off); off += (size_t)BS * LY * HD * 2;
  bf16* Vt = (bf16*)(ws + off); off += (size_t)BS * LY * HD * 2;  // (b,h,dk,y)
  bf16* Hb = (bf16*)(ws + off); off += (size_t)BS * LX * HD * 2;
  bf16* xbf = (bf16*)(ws + off); off += (size_t)BS * LX * D * 2;
  bf16* ybf = (bf16*)(ws + off); off += (size_t)BS * LY * D * 2;
  bf16* Wtq = (bf16*)(ws + off); off += (size_t)D * HD * 2;
  bf16* Wtk = (bf16*)(ws + off); off += (size_t)D * HD * 2;
  bf16* Wtv = (bf16*)(ws + off); off += (size_t)D * HD * 2;
  bf16* Wto = (bf16*)(ws + off); off += (size_t)HD * D * 2;

  dim3 blk(256);
  hipMemsetAsync(flags, 0, 32 * sizeof(int), stream);
  prep<<<dim3(6144), blk, 0, stream>>>(Wq, Wtq, Wk, Wtk, Wv, Wtv, Wo, Wto, x, xbf, y, ybf, mask, flags);
  qkv8<<<dim3(4, 16, 3), dim3(512), 0, stream>>>(xbf, ybf, Wtq, Wtk, Wtv, bq, bk, bv, Qb, Kb, Vt);
  attn12s<<<dim3(512), blk, 0, stream>>>(Qb, Kb, Vt, mask, flags, Hb);
  out_gemm<<<dim3(16, 32), blk, 0, stream>>>(Hb, Wto, bo, (float*)d_out);
}